// Round 7
// baseline (5151.498 us; speedup 1.0000x reference)
//
#include <hip/hip_runtime.h>

#define NN 100000
#define EE 800000
#define HH 128
#define LL 4
#define GG 64
#define BN_EPS 1e-5f
#define LN_EPS 1e-5f
#define POOL_CHUNK 64
#define NBUK ((NN + 255) >> 8)   // 391 buckets of 256 rows
#define CAP 8192
#define BCHUNK 8192

typedef __attribute__((ext_vector_type(8))) short short8;
typedef __attribute__((ext_vector_type(4))) float f32x4;

__device__ inline unsigned short bf16_rne(float f) {
    unsigned u = __float_as_uint(f);
    return (unsigned short)((u + 0x7FFF + ((u >> 16) & 1)) >> 16);
}
__device__ inline float bf16_to_f32(unsigned short h) {
    return __uint_as_float((unsigned)h << 16);
}

// ---------------- CSR build: bucket sort (256 rows / bucket) ----------------
// colidx entries are PACKED: (rowlocal_in_bucket << 17) | col   (col < 2^17)

__global__ __launch_bounds__(256) void bucket_count(const int* __restrict__ ei, int* __restrict__ bcnt) {
    __shared__ int h[NBUK];
    int tid = threadIdx.x;
    for (int i = tid; i < NBUK; i += 256) h[i] = 0;
    __syncthreads();
    for (int e = blockIdx.x * 256 + tid; e < 2 * EE; e += gridDim.x * 256) {
        int r = ei[e];
        int c = (e < EE) ? ei[e + EE] : ei[e - EE];
        if (r != c) atomicAdd(&h[r >> 8], 1);
    }
    __syncthreads();
    for (int i = tid; i < NBUK; i += 256) if (h[i]) atomicAdd(&bcnt[i], h[i]);
}

__global__ void bucket_scan(const int* __restrict__ bcnt, int* __restrict__ bbase,
                            int* __restrict__ bcur, int* __restrict__ rp) {
    __shared__ int sh[512];
    int t = threadIdx.x;
    sh[t] = (t < NBUK) ? bcnt[t] : 0;
    __syncthreads();
    for (int off = 1; off < 512; off <<= 1) {
        int x = (t >= off) ? sh[t - off] : 0;
        __syncthreads();
        sh[t] += x;
        __syncthreads();
    }
    if (t < NBUK) {
        int excl = (t > 0) ? sh[t - 1] : 0;
        bbase[t] = excl;
        bcur[t] = excl;
    }
    if (t == NBUK - 1) {
        bbase[NBUK] = sh[t];
        rp[NN] = sh[t];
    }
}

__global__ __launch_bounds__(256) void bucket_scatter(const int* __restrict__ ei, int* __restrict__ bcur,
                                                      int* __restrict__ pairs) {
    __shared__ int h[NBUK];
    __shared__ int curb[NBUK];
    int tid = threadIdx.x;
    for (int i = tid; i < NBUK; i += 256) h[i] = 0;
    __syncthreads();
    int base = blockIdx.x * BCHUNK;
#pragma unroll 4
    for (int k = 0; k < BCHUNK / 256; k++) {
        int e = base + k * 256 + tid;
        if (e < 2 * EE) {
            int r = ei[e];
            int c = (e < EE) ? ei[e + EE] : ei[e - EE];
            if (r != c) atomicAdd(&h[r >> 8], 1);
        }
    }
    __syncthreads();
    for (int i = tid; i < NBUK; i += 256) {
        int n = h[i];
        curb[i] = n ? atomicAdd(&bcur[i], n) : 0;
    }
    __syncthreads();
#pragma unroll 4
    for (int k = 0; k < BCHUNK / 256; k++) {
        int e = base + k * 256 + tid;
        if (e < 2 * EE) {
            int r = ei[e];
            int c = (e < EE) ? ei[e + EE] : ei[e - EE];
            if (r != c) {
                int p = atomicAdd(&curb[r >> 8], 1);
                pairs[p] = ((r & 255) << 17) | c;
            }
        }
    }
}

__global__ __launch_bounds__(256) void bucket_build(const int* __restrict__ pairs, const int* __restrict__ bbase,
                                                    int* __restrict__ rp, int* __restrict__ colidx) {
    __shared__ int hist[256], off[256], lcol[CAP];
    int b = blockIdx.x, tid = threadIdx.x;
    int s = bbase[b];
    int size = bbase[b + 1] - s;
    hist[tid] = 0;
    __syncthreads();
    for (int i = tid; i < size; i += 256) atomicAdd(&hist[pairs[s + i] >> 17], 1);
    __syncthreads();
    off[tid] = hist[tid];
    __syncthreads();
    for (int o = 1; o < 256; o <<= 1) {
        int x = (tid >= o) ? off[tid - o] : 0;
        __syncthreads();
        off[tid] += x;
        __syncthreads();
    }
    int excl = (tid > 0) ? off[tid - 1] : 0;
    int r = (b << 8) + tid;
    if (r < NN) rp[r] = s + excl;
    hist[tid] = excl;
    __syncthreads();
    if (size <= CAP) {
        for (int i = tid; i < size; i += 256) {
            int u = pairs[s + i];
            int p = atomicAdd(&hist[u >> 17], 1);
            lcol[p] = u;               // keep rowlocal bits
        }
        __syncthreads();
        for (int i = tid; i < size; i += 256) colidx[s + i] = lcol[i];
    } else {
        for (int i = tid; i < size; i += 256) {
            int u = pairs[s + i];
            int p = atomicAdd(&hist[u >> 17], 1);
            colidx[s + p] = u;         // keep rowlocal bits
        }
    }
}

// ---------------- weight prep: transpose + split fp32 -> bf16 hi/lo, FRAGMENT ORDER ----------------

__global__ void prep_w(const float* __restrict__ W0, const float* __restrict__ W1,
                       const float* __restrict__ W2,
                       short* __restrict__ wt_hi, short* __restrict__ wt_lo) {
    int i = blockIdx.x * 256 + threadIdx.x;
    if (i >= 9 * HH * HH) return;
    int mat = i >> 14, rem = i & 16383;
    int n = rem >> 7, k = rem & 127;
    const float* src = (mat == 0) ? W0 : ((mat <= 4) ? W1 + (size_t)(mat - 1) * HH * HH
                                                     : W2 + (size_t)(mat - 5) * HH * HH);
    float v = src[(size_t)k * HH + n];
    unsigned short h = bf16_rne(v);
    int off = (mat << 14) + (((k >> 3) * 8 + (n >> 4)) << 7) + ((n & 15) << 3) + (k & 7);
    wt_hi[off] = (short)h;
    wt_lo[off] = (short)bf16_rne(v - bf16_to_f32(h));
}

// ---------------- fused agg+GEMM1: 64 rows/block ----------------
// Phase A: u-tile = (1+eps)h + sum_nb h built in LDS (edge-parallel, LDS float atomics)
// Phase B: z1 = u @ W1 + b1 (W-hi staged into same LDS), column stats

__global__ __launch_bounds__(256, 4) void fused_g1(
    const unsigned* __restrict__ hbf_u,
    const int* __restrict__ rp, const int* __restrict__ colidx,
    const float* __restrict__ eps_l, int layer,
    const short* __restrict__ wt_hi, const short* __restrict__ wt_lo,
    const float* __restrict__ bias,
    float* __restrict__ Out,
    float* __restrict__ colsum, float* __restrict__ colsq)
{
    __shared__ __align__(16) char smem[64 * 132 * 4];   // 33792 B: u-tile, then W-hi
    __shared__ float stats[2 * HH];
    float (*uls)[132] = (float(*)[132])smem;
    short* wh = (short*)smem;

    int tid = threadIdx.x;
    int wave = tid >> 6, lane = tid & 63;
    int lrow = lane & 15, kgrp = lane >> 4;
    int r0 = blockIdx.x * 64;

    stats[tid] = 0.f;

    // ---- phase A: self term ----
    float eps1 = 1.0f + eps_l[layer];
    for (int i = tid; i < 4096; i += 256) {
        int row = i >> 6, uc = i & 63;
        int r = r0 + row;
        unsigned sv = (r < NN) ? hbf_u[(size_t)r * 64 + uc] : 0u;
        uls[row][2 * uc]     = __uint_as_float(sv << 16) * eps1;
        uls[row][2 * uc + 1] = __uint_as_float(sv & 0xFFFF0000u) * eps1;
    }
    __syncthreads();

    // ---- phase A: edge-parallel gather, 4 edges in flight per wave ----
    int rend = (r0 + 64 < NN) ? r0 + 64 : NN;
    int seg0 = rp[r0], seg1 = rp[rend];
    for (int e = seg0 + (wave << 2); e < seg1; e += 16) {
        unsigned pk[4], hv[4];
        bool val[4];
#pragma unroll
        for (int i = 0; i < 4; i++) {
            int ei = e + i;
            val[i] = ei < seg1;
            pk[i] = val[i] ? (unsigned)colidx[ei] : 0u;
            hv[i] = val[i] ? hbf_u[(size_t)(pk[i] & 0x1FFFF) * 64 + lane] : 0u;
        }
#pragma unroll
        for (int i = 0; i < 4; i++) {
            if (val[i]) {
                int rl = (pk[i] >> 17) & 63;
                atomicAdd(&uls[rl][2 * lane],     __uint_as_float(hv[i] << 16));
                atomicAdd(&uls[rl][2 * lane + 1], __uint_as_float(hv[i] & 0xFFFF0000u));
            }
        }
    }
    __syncthreads();

    // ---- read A-fragments from u-tile, convert to split-bf16 ----
    short8 ahi[4], alo[4];
#pragma unroll
    for (int ks = 0; ks < 4; ks++) {
        int kb = ks * 32 + kgrp * 8;
        float4 p0 = *(const float4*)&uls[wave * 16 + lrow][kb];
        float4 p1 = *(const float4*)&uls[wave * 16 + lrow][kb + 4];
        float av[8] = {p0.x, p0.y, p0.z, p0.w, p1.x, p1.y, p1.z, p1.w};
#pragma unroll
        for (int j = 0; j < 8; j++) {
            unsigned short hb = bf16_rne(av[j]);
            ahi[ks][j] = (short)hb;
            alo[ks][j] = (short)bf16_rne(av[j] - bf16_to_f32(hb));
        }
    }
    __syncthreads();

    // ---- stage W-hi into LDS (reuse u-tile memory) ----
    {
        const short8* src = (const short8*)wt_hi;
        short8* dst = (short8*)wh;
#pragma unroll
        for (int i = 0; i < 8; i++) dst[tid + i * 256] = src[tid + i * 256];
    }
    __syncthreads();

    f32x4 acc[8];
#pragma unroll
    for (int c = 0; c < 8; c++) acc[c] = (f32x4){0.f, 0.f, 0.f, 0.f};

#pragma unroll
    for (int ks = 0; ks < 4; ks++) {
        int fb = (ks * 4 + kgrp) * 8;
#pragma unroll
        for (int c = 0; c < 8; c++) {
            short8 whi = *(const short8*)(wh + ((fb + c) << 7) + (lrow << 3));
            short8 wlo = *(const short8*)(wt_lo + (size_t)((fb + c) << 7) + (lrow << 3));
            acc[c] = __builtin_amdgcn_mfma_f32_16x16x32_bf16(ahi[ks], whi, acc[c], 0, 0, 0);
            acc[c] = __builtin_amdgcn_mfma_f32_16x16x32_bf16(alo[ks], whi, acc[c], 0, 0, 0);
            acc[c] = __builtin_amdgcn_mfma_f32_16x16x32_bf16(ahi[ks], wlo, acc[c], 0, 0, 0);
        }
    }

    // ---- epilogue: z1 out + column stats ----
    float bv[8];
#pragma unroll
    for (int c = 0; c < 8; c++) bv[c] = bias[c * 16 + lrow];
    int lrb = wave * 16 + kgrp * 4;

    float ps[8], pq[8];
#pragma unroll
    for (int c = 0; c < 8; c++) { ps[c] = 0.f; pq[c] = 0.f; }
#pragma unroll
    for (int c = 0; c < 8; c++)
#pragma unroll
        for (int reg = 0; reg < 4; reg++) {
            int r = r0 + lrb + reg;
            if (r < NN) {
                float z = acc[c][reg] + bv[c];
                Out[(size_t)r * HH + c * 16 + lrow] = z;
                ps[c] += z; pq[c] += z * z;
            }
        }
#pragma unroll
    for (int c = 0; c < 8; c++) {
        ps[c] += __shfl_xor(ps[c], 16); pq[c] += __shfl_xor(pq[c], 16);
        ps[c] += __shfl_xor(ps[c], 32); pq[c] += __shfl_xor(pq[c], 32);
    }
    if (kgrp == 0) {
#pragma unroll
        for (int c = 0; c < 8; c++) {
            atomicAdd(&stats[c * 16 + lrow], ps[c]);
            atomicAdd(&stats[HH + c * 16 + lrow], pq[c]);
        }
    }
    __syncthreads();
    if (tid < HH) {
        atomicAdd(&colsum[tid], stats[tid]);
        atomicAdd(&colsq[tid], stats[HH + tid]);
    }
}

// ---------------- GEMM v6 (modes 0 and 2, unchanged from R6) ----------------

template<int MODE>
__global__ __launch_bounds__(256, 4) void gemm_v6(
    const float* __restrict__ A,
    const short* __restrict__ wt_hi, const short* __restrict__ wt_lo,
    const float* __restrict__ bias,
    float* __restrict__ Out,
    float* __restrict__ colsum, float* __restrict__ colsq,
    const float* __restrict__ bng, const float* __restrict__ bnb,
    const float* __restrict__ lng, const float* __restrict__ lnb,
    float* __restrict__ Hbuf, unsigned short* __restrict__ hbf_out)
{
    __shared__ short wh[HH * HH];
    __shared__ float stats[2 * HH];
    int tid = threadIdx.x;
    int wave = tid >> 6, lane = tid & 63;
    int lrow = lane & 15, kgrp = lane >> 4;
    int r0 = blockIdx.x * 64;
    int arow = r0 + wave * 16 + lrow;

    {
        const short8* src = (const short8*)wt_hi;
        short8* dst = (short8*)wh;
#pragma unroll
        for (int i = 0; i < 8; i++) dst[tid + i * 256] = src[tid + i * 256];
    }
    if (MODE == 2) {
        if (tid < HH) {
            float m = colsum[tid] * (1.f / NN);
            float v = colsq[tid] * (1.f / NN) - m * m;
            float a = bng[tid] * rsqrtf(v + BN_EPS);
            stats[tid] = a;
            stats[HH + tid] = bnb[tid] - m * a;
        }
    }

    float4 a0[4], a1[4];
    if (arow < NN) {
#pragma unroll
        for (int ks = 0; ks < 4; ks++) {
            int kb = ks * 32 + kgrp * 8;
            a0[ks] = *(const float4*)(A + (size_t)arow * HH + kb);
            a1[ks] = *(const float4*)(A + (size_t)arow * HH + kb + 4);
        }
    } else {
#pragma unroll
        for (int ks = 0; ks < 4; ks++) {
            a0[ks] = make_float4(0.f, 0.f, 0.f, 0.f);
            a1[ks] = a0[ks];
        }
    }
    __syncthreads();

    f32x4 acc[8];
#pragma unroll
    for (int c = 0; c < 8; c++) acc[c] = (f32x4){0.f, 0.f, 0.f, 0.f};

#pragma unroll
    for (int ks = 0; ks < 4; ks++) {
        int kb = ks * 32 + kgrp * 8;
        float av[8] = {a0[ks].x, a0[ks].y, a0[ks].z, a0[ks].w,
                       a1[ks].x, a1[ks].y, a1[ks].z, a1[ks].w};
        if (MODE == 2) {
#pragma unroll
            for (int j = 0; j < 8; j++)
                av[j] = fmaxf(fmaf(av[j], stats[kb + j], stats[HH + kb + j]), 0.f);
        }
        short8 ahi, alo;
#pragma unroll
        for (int j = 0; j < 8; j++) {
            unsigned short hb = bf16_rne(av[j]);
            ahi[j] = (short)hb;
            alo[j] = (short)bf16_rne(av[j] - bf16_to_f32(hb));
        }
        int fb = (ks * 4 + kgrp) * 8;
#pragma unroll
        for (int c = 0; c < 8; c++) {
            short8 whi = *(const short8*)(wh + ((fb + c) << 7) + (lrow << 3));
            short8 wlo = *(const short8*)(wt_lo + (size_t)((fb + c) << 7) + (lrow << 3));
            acc[c] = __builtin_amdgcn_mfma_f32_16x16x32_bf16(ahi, whi, acc[c], 0, 0, 0);
            acc[c] = __builtin_amdgcn_mfma_f32_16x16x32_bf16(alo, whi, acc[c], 0, 0, 0);
            acc[c] = __builtin_amdgcn_mfma_f32_16x16x32_bf16(ahi, wlo, acc[c], 0, 0, 0);
        }
    }

    float bv[8];
#pragma unroll
    for (int c = 0; c < 8; c++) bv[c] = bias[c * 16 + lrow];
    int lrb = wave * 16 + kgrp * 4;

    if (MODE == 0) {
        __syncthreads();
        unsigned short* hst = (unsigned short*)wh;
#pragma unroll
        for (int c = 0; c < 8; c++)
#pragma unroll
            for (int reg = 0; reg < 4; reg++) {
                float z = acc[c][reg] + bv[c];
                int r = r0 + lrb + reg;
                if (r < NN) Out[(size_t)r * HH + c * 16 + lrow] = z;
                hst[(lrb + reg) * HH + c * 16 + lrow] = bf16_rne(z);
            }
        __syncthreads();
#pragma unroll
        for (int i = 0; i < 4; i++) {
            int idx = tid + i * 256;
            int row = idx >> 4;
            int r = r0 + row;
            if (r < NN)
                *(uint4*)(hbf_out + (size_t)r * HH + (idx & 15) * 8) = ((const uint4*)wh)[idx];
        }
    } else {
        float lg[8], lb[8];
#pragma unroll
        for (int c = 0; c < 8; c++) {
            lg[c] = lng[c * 16 + lrow];
            lb[c] = lnb[c * 16 + lrow];
        }
        __syncthreads();
        unsigned short* hst = (unsigned short*)wh;
#pragma unroll
        for (int reg = 0; reg < 4; reg++) {
            int r = r0 + lrb + reg;
            if (r < NN) {
                float tv[8];
                float s = 0.f, q = 0.f;
#pragma unroll
                for (int c = 0; c < 8; c++) {
                    float hold = Hbuf[(size_t)r * HH + c * 16 + lrow];
                    tv[c] = hold + fmaxf(acc[c][reg] + bv[c], 0.f);
                    s += tv[c]; q += tv[c] * tv[c];
                }
#pragma unroll
                for (int m = 1; m < 16; m <<= 1) {
                    s += __shfl_xor(s, m);
                    q += __shfl_xor(q, m);
                }
                float mu = s * (1.f / 128.f);
                float var = q * (1.f / 128.f) - mu * mu;
                float rs = rsqrtf(var + LN_EPS);
#pragma unroll
                for (int c = 0; c < 8; c++) {
                    float o = (tv[c] - mu) * rs * lg[c] + lb[c];
                    Hbuf[(size_t)r * HH + c * 16 + lrow] = o;
                    if (hbf_out) hst[(lrb + reg) * HH + c * 16 + lrow] = bf16_rne(o);
                }
            }
        }
        if (hbf_out) {
            __syncthreads();
#pragma unroll
            for (int i = 0; i < 4; i++) {
                int idx = tid + i * 256;
                int row = idx >> 4;
                int r = r0 + row;
                if (r < NN)
                    *(uint4*)(hbf_out + (size_t)r * HH + (idx & 15) * 8) = ((const uint4*)wh)[idx];
            }
        }
    }
}

// ---------------- pooling ----------------

__global__ void pool_kernel(const float* __restrict__ h, const int* __restrict__ batch,
                            float* __restrict__ psum, float* __restrict__ pcnt)
{
    int t = threadIdx.x;  // 128
    int n0 = blockIdx.x * POOL_CHUNK;
    int n1 = n0 + POOL_CHUNK; if (n1 > NN) n1 = NN;
    if (n0 >= NN) return;
    float acc = 0.f;
    int cur = batch[n0];
    int cnt = 0;
    for (int n = n0; n < n1; n++) {
        int g = batch[n];
        if (g != cur) {
            atomicAdd(&psum[cur * HH + t], acc);
            if (t == 0) atomicAdd(&pcnt[cur], (float)cnt);
            acc = 0.f; cnt = 0; cur = g;
        }
        acc += h[(size_t)n * HH + t];
        cnt++;
    }
    atomicAdd(&psum[cur * HH + t], acc);
    if (t == 0) atomicAdd(&pcnt[cur], (float)cnt);
}

__global__ void pool_final(const float* __restrict__ psum, const float* __restrict__ pcnt,
                           float* __restrict__ out)
{
    int i = blockIdx.x * blockDim.x + threadIdx.x;
    if (i < GG * HH) {
        float c = pcnt[i >> 7];
        out[i] = psum[i] / fmaxf(c, 1.f);
    }
}

// ---------------- launch ----------------

extern "C" void kernel_launch(void* const* d_in, const int* in_sizes, int n_in,
                              void* d_out, int out_size, void* d_ws, size_t ws_size,
                              hipStream_t stream)
{
    const float* x     = (const float*)d_in[0];
    const float* W0    = (const float*)d_in[1];
    const float* b0    = (const float*)d_in[2];
    const float* eps_l = (const float*)d_in[3];
    const float* W1    = (const float*)d_in[4];
    const float* b1    = (const float*)d_in[5];
    const float* bng   = (const float*)d_in[6];
    const float* bnb   = (const float*)d_in[7];
    const float* W2    = (const float*)d_in[8];
    const float* b2    = (const float*)d_in[9];
    const float* lng   = (const float*)d_in[10];
    const float* lnb   = (const float*)d_in[11];
    const int*   ei    = (const int*)d_in[12];
    const int*   batch = (const int*)d_in[13];
    float* out = (float*)d_out;

    char* ws = (char*)d_ws;
    size_t off = 0;
    auto alloc = [&](size_t bytes) -> void* {
        void* p = ws + off;
        off += (bytes + 255) & ~(size_t)255;
        return p;
    };
    float* hbuf   = (float*)alloc((size_t)NN * HH * 4);
    float* ubuf   = (float*)alloc((size_t)NN * HH * 4);   // z1
    unsigned short* hbf = (unsigned short*)alloc((size_t)NN * HH * 2);
    int*   colidx = (int*)alloc((size_t)2 * EE * 4);
    int*   pairs  = (int*)alloc((size_t)2 * EE * 4);
    int*   rp     = (int*)alloc((size_t)(NN + 1) * 4);
    int*   bcnt   = (int*)alloc((NBUK + 1) * 4);
    int*   bbase  = (int*)alloc((NBUK + 1) * 4);
    int*   bcur   = (int*)alloc((NBUK + 1) * 4);
    float* colsum = (float*)alloc((size_t)LL * HH * 2 * 4);  // [l][sum|sq][HH]
    float* psum   = (float*)alloc((size_t)GG * HH * 4);
    float* pcnt   = (float*)alloc(GG * 4);
    short* wt_hi  = (short*)alloc((size_t)9 * HH * HH * 2);
    short* wt_lo  = (short*)alloc((size_t)9 * HH * HH * 2);

    hipMemsetAsync(bcnt, 0, (NBUK + 1) * 4, stream);
    hipMemsetAsync(colsum, 0, (size_t)LL * HH * 2 * 4, stream);
    hipMemsetAsync(psum, 0, (size_t)GG * HH * 4, stream);
    hipMemsetAsync(pcnt, 0, GG * 4, stream);

    prep_w<<<(9 * HH * HH + 255) / 256, 256, 0, stream>>>(W0, W1, W2, wt_hi, wt_lo);

    bucket_count<<<512, 256, 0, stream>>>(ei, bcnt);
    bucket_scan<<<1, 512, 0, stream>>>(bcnt, bbase, bcur, rp);
    bucket_scatter<<<(2 * EE + BCHUNK - 1) / BCHUNK, 256, 0, stream>>>(ei, bcur, pairs);
    bucket_build<<<NBUK, 256, 0, stream>>>(pairs, bbase, rp, colidx);

    int gb = (NN + 63) / 64;
    // encode: hbuf = x @ W0 + b0 (+ hbf mirror)
    gemm_v6<0><<<gb, 256, 0, stream>>>(x, wt_hi, wt_lo, b0, hbuf,
                                       nullptr, nullptr, nullptr, nullptr, nullptr, nullptr,
                                       nullptr, hbf);

    for (int l = 0; l < LL; l++) {
        float* cs = colsum + (size_t)l * HH * 2;
        float* cq = cs + HH;
        // z1 = ((1+eps)h + sum_nb h) @ W1 + b1  (agg fused, u never hits HBM) + col stats
        fused_g1<<<gb, 256, 0, stream>>>((const unsigned*)hbf, rp, colidx, eps_l, l,
                                         wt_hi + (size_t)(1 + l) * HH * HH,
                                         wt_lo + (size_t)(1 + l) * HH * HH, b1 + l * HH, ubuf,
                                         cs, cq);
        // h = LN(h + relu(relu(BN(z1)) @ W2 + b2)) (+ hbf mirror except last layer)
        gemm_v6<2><<<gb, 256, 0, stream>>>(ubuf, wt_hi + (size_t)(5 + l) * HH * HH,
                                           wt_lo + (size_t)(5 + l) * HH * HH, b2 + l * HH, nullptr,
                                           cs, cq, bng + l * HH, bnb + l * HH,
                                           lng + l * HH, lnb + l * HH, hbuf,
                                           (l == LL - 1) ? nullptr : hbf);
    }

    pool_kernel<<<(NN + POOL_CHUNK - 1) / POOL_CHUNK, 128, 0, stream>>>(hbuf, batch, psum, pcnt);
    pool_final<<<(GG * HH + 255) / 256, 256, 0, stream>>>(psum, pcnt, out);
}

// Round 8
// 834.477 us; speedup vs baseline: 6.1733x; 6.1733x over previous
//
#include <hip/hip_runtime.h>

#define NN 100000
#define EE 800000
#define HH 128
#define LL 4
#define GG 64
#define BN_EPS 1e-5f
#define LN_EPS 1e-5f
#define POOL_CHUNK 64
#define NBUK ((NN + 255) >> 8)   // 391 buckets of 256 rows
#define CAP 8192                 // fixed bucket capacity (max observed ~4.5k)
#define BCHUNK 8192

typedef __attribute__((ext_vector_type(8))) short short8;
typedef __attribute__((ext_vector_type(4))) float f32x4;

__device__ inline unsigned short bf16_rne(float f) {
    unsigned u = __float_as_uint(f);
    return (unsigned short)((u + 0x7FFF + ((u >> 16) & 1)) >> 16);
}
__device__ inline float bf16_to_f32(unsigned short h) {
    return __uint_as_float((unsigned)h << 16);
}

// ---------------- CSR build: fixed-capacity bucket sort (256 rows / bucket) ----------------

__global__ void init_bcur(int* __restrict__ bcur) {
    int i = blockIdx.x * 256 + threadIdx.x;
    if (i < NBUK) bcur[i] = i * CAP;
}

__global__ __launch_bounds__(256) void bucket_scatter(const int* __restrict__ ei, int* __restrict__ bcur,
                                                      int* __restrict__ pairs) {
    __shared__ int h[NBUK];
    __shared__ int curb[NBUK];
    int tid = threadIdx.x;
    for (int i = tid; i < NBUK; i += 256) h[i] = 0;
    __syncthreads();
    int base = blockIdx.x * BCHUNK;
#pragma unroll 4
    for (int k = 0; k < BCHUNK / 256; k++) {
        int e = base + k * 256 + tid;
        if (e < 2 * EE) {
            int r = ei[e];
            int c = (e < EE) ? ei[e + EE] : ei[e - EE];
            if (r != c) atomicAdd(&h[r >> 8], 1);
        }
    }
    __syncthreads();
    for (int i = tid; i < NBUK; i += 256) {
        int n = h[i];
        curb[i] = n ? atomicAdd(&bcur[i], n) : 0;
    }
    __syncthreads();
#pragma unroll 4
    for (int k = 0; k < BCHUNK / 256; k++) {
        int e = base + k * 256 + tid;
        if (e < 2 * EE) {
            int r = ei[e];
            int c = (e < EE) ? ei[e + EE] : ei[e - EE];
            if (r != c) {
                int p = atomicAdd(&curb[r >> 8], 1);
                pairs[p] = ((r & 255) << 17) | c;
            }
        }
    }
}

__global__ __launch_bounds__(256) void bucket_build(const int* __restrict__ pairs, const int* __restrict__ bcur,
                                                    int* __restrict__ rp, int* __restrict__ re,
                                                    int* __restrict__ colidx) {
    __shared__ int hist[256], off[256], lcol[CAP];
    int b = blockIdx.x, tid = threadIdx.x;
    int s = b * CAP;
    int size = bcur[b] - s;
    hist[tid] = 0;
    __syncthreads();
    for (int i = tid; i < size; i += 256) atomicAdd(&hist[pairs[s + i] >> 17], 1);
    __syncthreads();
    off[tid] = hist[tid];
    __syncthreads();
    for (int o = 1; o < 256; o <<= 1) {
        int x = (tid >= o) ? off[tid - o] : 0;
        __syncthreads();
        off[tid] += x;
        __syncthreads();
    }
    int excl = (tid > 0) ? off[tid - 1] : 0;
    int r = (b << 8) + tid;
    if (r < NN) { rp[r] = s + excl; re[r] = s + off[tid]; }
    hist[tid] = excl;
    __syncthreads();
    for (int i = tid; i < size; i += 256) {
        int u = pairs[s + i];
        int p = atomicAdd(&hist[u >> 17], 1);
        lcol[p] = u & 0x1FFFF;
    }
    __syncthreads();
    for (int i = tid; i < size; i += 256) colidx[s + i] = lcol[i];
}

// ---------------- weight prep: transpose + split fp32 -> bf16 hi/lo, FRAGMENT ORDER ----------------

__global__ void prep_w(const float* __restrict__ W0, const float* __restrict__ W1,
                       const float* __restrict__ W2,
                       short* __restrict__ wt_hi, short* __restrict__ wt_lo) {
    int i = blockIdx.x * 256 + threadIdx.x;
    if (i >= 9 * HH * HH) return;
    int mat = i >> 14, rem = i & 16383;
    int n = rem >> 7, k = rem & 127;
    const float* src = (mat == 0) ? W0 : ((mat <= 4) ? W1 + (size_t)(mat - 1) * HH * HH
                                                     : W2 + (size_t)(mat - 5) * HH * HH);
    float v = src[(size_t)k * HH + n];
    unsigned short h = bf16_rne(v);
    int off = (mat << 14) + (((k >> 3) * 8 + (n >> 4)) << 7) + ((n & 15) << 3) + (k & 7);
    wt_hi[off] = (short)h;
    wt_lo[off] = (short)bf16_rne(v - bf16_to_f32(h));
}

// ---------------- aggregation: u = (1+eps)*h + sum_nb h[nb], gather from bf16 h ----------------

__global__ __launch_bounds__(256) void agg_kernel(
    const unsigned int* __restrict__ hbf, const int* __restrict__ rp, const int* __restrict__ re,
    const int* __restrict__ colidx,
    const float* __restrict__ eps_l, int layer, float* __restrict__ u)
{
    int node = blockIdx.x * 4 + (threadIdx.x >> 6);
    if (node >= NN) return;
    int lane = threadIdx.x & 63;
    float eps1 = 1.0f + eps_l[layer];
    unsigned sv = hbf[node * 64 + lane];
    float ax = __uint_as_float(sv << 16) * eps1;
    float ay = __uint_as_float(sv & 0xFFFF0000u) * eps1;
    int i = rp[node], end = re[node];
    for (; i + 4 <= end; i += 4) {
        unsigned v0 = hbf[colidx[i] * 64 + lane];
        unsigned v1 = hbf[colidx[i + 1] * 64 + lane];
        unsigned v2 = hbf[colidx[i + 2] * 64 + lane];
        unsigned v3 = hbf[colidx[i + 3] * 64 + lane];
        ax += __uint_as_float(v0 << 16) + __uint_as_float(v1 << 16)
            + __uint_as_float(v2 << 16) + __uint_as_float(v3 << 16);
        ay += __uint_as_float(v0 & 0xFFFF0000u) + __uint_as_float(v1 & 0xFFFF0000u)
            + __uint_as_float(v2 & 0xFFFF0000u) + __uint_as_float(v3 & 0xFFFF0000u);
    }
    for (; i < end; i++) {
        unsigned v = hbf[colidx[i] * 64 + lane];
        ax += __uint_as_float(v << 16);
        ay += __uint_as_float(v & 0xFFFF0000u);
    }
    ((float2*)(u + (size_t)node * HH))[lane] = make_float2(ax, ay);
}

// ---------------- GEMM v7: 64 rows/block (4 waves x 16 rows), W-hi in LDS, A prefetched ----
// MODE 0: hbf = bf16(x @ W0 + bias)                       [A fp32]
// MODE 1: z1  = bf16(A @ W1 + bias); column stats         [A = u, fp32]
// MODE 2: A' = relu(BN(z1)); hbf = bf16(LN(h_old + relu(A'@W2 + bias)))   [A = z1, bf16]

template<int MODE>
__global__ __launch_bounds__(256, 4) void gemm_v7(
    const void* __restrict__ Ain,
    const short* __restrict__ wt_hi, const short* __restrict__ wt_lo,
    const float* __restrict__ bias,
    unsigned short* __restrict__ z1_out,
    float* __restrict__ colsum, float* __restrict__ colsq,
    const float* __restrict__ bng, const float* __restrict__ bnb,
    const float* __restrict__ lng, const float* __restrict__ lnb,
    unsigned short* __restrict__ hbf)
{
    __shared__ short wh[HH * HH];    // 32 KB W-hi; reused post-K-loop as bf16 row-tile stage
    __shared__ float stats[2 * HH];  // mode1: csum|csq ; mode2: bsc|bsh
    int tid = threadIdx.x;
    int wave = tid >> 6, lane = tid & 63;
    int lrow = lane & 15, kgrp = lane >> 4;
    int r0 = blockIdx.x * 64;
    int arow = r0 + wave * 16 + lrow;

    // stage W-hi (fragment order, coalesced, conflict-free)
    {
        const short8* src = (const short8*)wt_hi;
        short8* dst = (short8*)wh;
#pragma unroll
        for (int i = 0; i < 8; i++) dst[tid + i * 256] = src[tid + i * 256];
    }
    if (MODE == 1) stats[tid] = 0.f;
    if (MODE == 2 && tid < HH) {
        float m = colsum[tid] * (1.f / NN);
        float v = colsq[tid] * (1.f / NN) - m * m;
        float a = bng[tid] * rsqrtf(v + BN_EPS);
        stats[tid] = a;
        stats[HH + tid] = bnb[tid] - m * a;
    }

    // prefetch all A fragments
    float4 a0[4], a1[4];
    short8 az[4];
    if (MODE == 2) {
        const unsigned short* Az = (const unsigned short*)Ain;
        if (arow < NN) {
#pragma unroll
            for (int ks = 0; ks < 4; ks++)
                az[ks] = *(const short8*)(Az + (size_t)arow * HH + ks * 32 + kgrp * 8);
        } else {
#pragma unroll
            for (int ks = 0; ks < 4; ks++) az[ks] = (short8){0,0,0,0,0,0,0,0};
        }
    } else {
        const float* Af = (const float*)Ain;
        if (arow < NN) {
#pragma unroll
            for (int ks = 0; ks < 4; ks++) {
                int kb = ks * 32 + kgrp * 8;
                a0[ks] = *(const float4*)(Af + (size_t)arow * HH + kb);
                a1[ks] = *(const float4*)(Af + (size_t)arow * HH + kb + 4);
            }
        } else {
#pragma unroll
            for (int ks = 0; ks < 4; ks++) {
                a0[ks] = make_float4(0.f, 0.f, 0.f, 0.f);
                a1[ks] = a0[ks];
            }
        }
    }
    __syncthreads();

    f32x4 acc[8];
#pragma unroll
    for (int c = 0; c < 8; c++) acc[c] = (f32x4){0.f, 0.f, 0.f, 0.f};

#pragma unroll
    for (int ks = 0; ks < 4; ks++) {
        int kb = ks * 32 + kgrp * 8;
        float av[8];
        if (MODE == 2) {
#pragma unroll
            for (int j = 0; j < 8; j++) {
                float zb = bf16_to_f32((unsigned short)az[ks][j]);
                av[j] = fmaxf(fmaf(zb, stats[kb + j], stats[HH + kb + j]), 0.f);
            }
        } else {
            av[0] = a0[ks].x; av[1] = a0[ks].y; av[2] = a0[ks].z; av[3] = a0[ks].w;
            av[4] = a1[ks].x; av[5] = a1[ks].y; av[6] = a1[ks].z; av[7] = a1[ks].w;
        }
        short8 ahi, alo;
#pragma unroll
        for (int j = 0; j < 8; j++) {
            unsigned short hb = bf16_rne(av[j]);
            ahi[j] = (short)hb;
            alo[j] = (short)bf16_rne(av[j] - bf16_to_f32(hb));
        }
        int fb = (ks * 4 + kgrp) * 8;
#pragma unroll
        for (int c = 0; c < 8; c++) {
            short8 whi = *(const short8*)(wh + ((fb + c) << 7) + (lrow << 3));
            short8 wlo = *(const short8*)(wt_lo + (size_t)((fb + c) << 7) + (lrow << 3));
            acc[c] = __builtin_amdgcn_mfma_f32_16x16x32_bf16(ahi, whi, acc[c], 0, 0, 0);
            acc[c] = __builtin_amdgcn_mfma_f32_16x16x32_bf16(alo, whi, acc[c], 0, 0, 0);
            acc[c] = __builtin_amdgcn_mfma_f32_16x16x32_bf16(ahi, wlo, acc[c], 0, 0, 0);
        }
    }

    float bv[8];
#pragma unroll
    for (int c = 0; c < 8; c++) bv[c] = bias[c * 16 + lrow];
    int lrb = wave * 16 + kgrp * 4;
    unsigned short* hst = (unsigned short*)wh;

    if (MODE == 0) {
        __syncthreads();
#pragma unroll
        for (int c = 0; c < 8; c++)
#pragma unroll
            for (int reg = 0; reg < 4; reg++)
                hst[(lrb + reg) * HH + c * 16 + lrow] = bf16_rne(acc[c][reg] + bv[c]);
        __syncthreads();
#pragma unroll
        for (int i = 0; i < 4; i++) {
            int idx = tid + i * 256;
            int r = r0 + (idx >> 4);
            if (r < NN)
                *(uint4*)(hbf + (size_t)r * HH + (idx & 15) * 8) = ((const uint4*)wh)[idx];
        }
    } else if (MODE == 1) {
        __syncthreads();
        float ps[8], pq[8];
#pragma unroll
        for (int c = 0; c < 8; c++) { ps[c] = 0.f; pq[c] = 0.f; }
#pragma unroll
        for (int c = 0; c < 8; c++)
#pragma unroll
            for (int reg = 0; reg < 4; reg++) {
                float z = acc[c][reg] + bv[c];
                hst[(lrb + reg) * HH + c * 16 + lrow] = bf16_rne(z);
                if (r0 + lrb + reg < NN) { ps[c] += z; pq[c] += z * z; }
            }
#pragma unroll
        for (int c = 0; c < 8; c++) {
            ps[c] += __shfl_xor(ps[c], 16); pq[c] += __shfl_xor(pq[c], 16);
            ps[c] += __shfl_xor(ps[c], 32); pq[c] += __shfl_xor(pq[c], 32);
        }
        if (kgrp == 0) {
#pragma unroll
            for (int c = 0; c < 8; c++) {
                atomicAdd(&stats[c * 16 + lrow], ps[c]);
                atomicAdd(&stats[HH + c * 16 + lrow], pq[c]);
            }
        }
        __syncthreads();
#pragma unroll
        for (int i = 0; i < 4; i++) {
            int idx = tid + i * 256;
            int r = r0 + (idx >> 4);
            if (r < NN)
                *(uint4*)(z1_out + (size_t)r * HH + (idx & 15) * 8) = ((const uint4*)wh)[idx];
        }
        if (tid < HH) {
            atomicAdd(&colsum[tid], stats[tid]);
            atomicAdd(&colsq[tid], stats[HH + tid]);
        }
    } else {
        float lg[8], lb[8];
#pragma unroll
        for (int c = 0; c < 8; c++) {
            lg[c] = lng[c * 16 + lrow];
            lb[c] = lnb[c * 16 + lrow];
        }
        __syncthreads();
        // coalesced load of old-h tile into LDS
#pragma unroll
        for (int i = 0; i < 4; i++) {
            int idx = tid + i * 256;
            int r = r0 + (idx >> 4);
            uint4 v = make_uint4(0, 0, 0, 0);
            if (r < NN) v = *(const uint4*)(hbf + (size_t)r * HH + (idx & 15) * 8);
            ((uint4*)wh)[idx] = v;
        }
        __syncthreads();
#pragma unroll
        for (int reg = 0; reg < 4; reg++) {
            int r = r0 + lrb + reg;
            if (r < NN) {   // uniform within each 16-lane shfl group
                float tv[8];
                float s = 0.f, q = 0.f;
#pragma unroll
                for (int c = 0; c < 8; c++) {
                    float hold = bf16_to_f32(hst[(lrb + reg) * HH + c * 16 + lrow]);
                    tv[c] = hold + fmaxf(acc[c][reg] + bv[c], 0.f);
                    s += tv[c]; q += tv[c] * tv[c];
                }
#pragma unroll
                for (int m = 1; m < 16; m <<= 1) {
                    s += __shfl_xor(s, m);
                    q += __shfl_xor(q, m);
                }
                float mu = s * (1.f / 128.f);
                float var = q * (1.f / 128.f) - mu * mu;
                float rs = rsqrtf(var + LN_EPS);
#pragma unroll
                for (int c = 0; c < 8; c++)
                    hst[(lrb + reg) * HH + c * 16 + lrow] =
                        bf16_rne((tv[c] - mu) * rs * lg[c] + lb[c]);
            }
        }
        __syncthreads();
#pragma unroll
        for (int i = 0; i < 4; i++) {
            int idx = tid + i * 256;
            int r = r0 + (idx >> 4);
            if (r < NN)
                *(uint4*)(hbf + (size_t)r * HH + (idx & 15) * 8) = ((const uint4*)wh)[idx];
        }
    }
}

// ---------------- pooling (reads bf16 h) ----------------

__global__ void pool_kernel(const unsigned short* __restrict__ h, const int* __restrict__ batch,
                            float* __restrict__ psum, float* __restrict__ pcnt)
{
    int t = threadIdx.x;  // 128
    int n0 = blockIdx.x * POOL_CHUNK;
    int n1 = n0 + POOL_CHUNK; if (n1 > NN) n1 = NN;
    if (n0 >= NN) return;
    float acc = 0.f;
    int cur = batch[n0];
    int cnt = 0;
    for (int n = n0; n < n1; n++) {
        int g = batch[n];
        if (g != cur) {
            atomicAdd(&psum[cur * HH + t], acc);
            if (t == 0) atomicAdd(&pcnt[cur], (float)cnt);
            acc = 0.f; cnt = 0; cur = g;
        }
        acc += bf16_to_f32(h[(size_t)n * HH + t]);
        cnt++;
    }
    atomicAdd(&psum[cur * HH + t], acc);
    if (t == 0) atomicAdd(&pcnt[cur], (float)cnt);
}

__global__ void pool_final(const float* __restrict__ psum, const float* __restrict__ pcnt,
                           float* __restrict__ out)
{
    int i = blockIdx.x * blockDim.x + threadIdx.x;
    if (i < GG * HH) {
        float c = pcnt[i >> 7];
        out[i] = psum[i] / fmaxf(c, 1.f);
    }
}

// ---------------- launch ----------------

extern "C" void kernel_launch(void* const* d_in, const int* in_sizes, int n_in,
                              void* d_out, int out_size, void* d_ws, size_t ws_size,
                              hipStream_t stream)
{
    const float* x     = (const float*)d_in[0];
    const float* W0    = (const float*)d_in[1];
    const float* b0    = (const float*)d_in[2];
    const float* eps_l = (const float*)d_in[3];
    const float* W1    = (const float*)d_in[4];
    const float* b1    = (const float*)d_in[5];
    const float* bng   = (const float*)d_in[6];
    const float* bnb   = (const float*)d_in[7];
    const float* W2    = (const float*)d_in[8];
    const float* b2    = (const float*)d_in[9];
    const float* lng   = (const float*)d_in[10];
    const float* lnb   = (const float*)d_in[11];
    const int*   ei    = (const int*)d_in[12];
    const int*   batch = (const int*)d_in[13];
    float* out = (float*)d_out;

    char* ws = (char*)d_ws;
    size_t off = 0;
    auto alloc = [&](size_t bytes) -> void* {
        void* p = ws + off;
        off += (bytes + 255) & ~(size_t)255;
        return p;
    };
    unsigned short* hbf = (unsigned short*)alloc((size_t)NN * HH * 2);  // h (bf16) — the only h
    unsigned short* z1  = (unsigned short*)alloc((size_t)NN * HH * 2);  // z1 (bf16)
    float* ubuf   = (float*)alloc((size_t)NN * HH * 4);                 // u (fp32)
    int*   colidx = (int*)alloc((size_t)NBUK * CAP * 4);
    int*   pairs  = (int*)alloc((size_t)NBUK * CAP * 4);
    int*   rp     = (int*)alloc((size_t)NN * 4);
    int*   re     = (int*)alloc((size_t)NN * 4);
    int*   bcur   = (int*)alloc((NBUK + 1) * 4);
    float* colsum = (float*)alloc((size_t)LL * HH * 2 * 4);  // [l][sum|sq][HH]
    float* psum   = (float*)alloc((size_t)GG * HH * 4);
    float* pcnt   = (float*)alloc(GG * 4);
    short* wt_hi  = (short*)alloc((size_t)9 * HH * HH * 2);
    short* wt_lo  = (short*)alloc((size_t)9 * HH * HH * 2);

    hipMemsetAsync(colsum, 0, (size_t)LL * HH * 2 * 4, stream);
    hipMemsetAsync(psum, 0, (size_t)GG * HH * 4, stream);
    hipMemsetAsync(pcnt, 0, GG * 4, stream);

    init_bcur<<<(NBUK + 255) / 256, 256, 0, stream>>>(bcur);
    prep_w<<<(9 * HH * HH + 255) / 256, 256, 0, stream>>>(W0, W1, W2, wt_hi, wt_lo);

    bucket_scatter<<<(2 * EE + BCHUNK - 1) / BCHUNK, 256, 0, stream>>>(ei, bcur, pairs);
    bucket_build<<<NBUK, 256, 0, stream>>>(pairs, bcur, rp, re, colidx);

    int gb = (NN + 63) / 64;
    // encode: h = bf16(x @ W0 + b0)
    gemm_v7<0><<<gb, 256, 0, stream>>>(x, wt_hi, wt_lo, b0, nullptr,
                                       nullptr, nullptr, nullptr, nullptr, nullptr, nullptr, hbf);

    for (int l = 0; l < LL; l++) {
        float* cs = colsum + (size_t)l * HH * 2;
        float* cq = cs + HH;
        // u = (1+eps)h + sum_nb h  (gather from bf16 h)
        agg_kernel<<<(NN + 3) / 4, 256, 0, stream>>>((const unsigned*)hbf, rp, re, colidx,
                                                     eps_l, l, ubuf);
        // z1 = bf16(u @ W1 + b1) + column stats
        gemm_v7<1><<<gb, 256, 0, stream>>>(ubuf, wt_hi + (size_t)(1 + l) * HH * HH,
                                           wt_lo + (size_t)(1 + l) * HH * HH, b1 + l * HH, z1,
                                           cs, cq, nullptr, nullptr, nullptr, nullptr, nullptr);
        // h = bf16(LN(h + relu(relu(BN(z1)) @ W2 + b2)))
        gemm_v7<2><<<gb, 256, 0, stream>>>(z1, wt_hi + (size_t)(5 + l) * HH * HH,
                                           wt_lo + (size_t)(5 + l) * HH * HH, b2 + l * HH, nullptr,
                                           cs, cq, bng + l * HH, bnb + l * HH,
                                           lng + l * HH, lnb + l * HH, hbf);
    }

    pool_kernel<<<(NN + POOL_CHUNK - 1) / POOL_CHUNK, 128, 0, stream>>>(hbf, batch, psum, pcnt);
    pool_final<<<(GG * HH + 255) / 256, 256, 0, stream>>>(psum, pcnt, out);
}

// Round 9
// 725.786 us; speedup vs baseline: 7.0978x; 1.1498x over previous
//
#include <hip/hip_runtime.h>

#define NN 100000
#define EE 800000
#define HH 128
#define LL 4
#define GG 64
#define BN_EPS 1e-5f
#define LN_EPS 1e-5f
#define POOL_CHUNK 64
#define NBUK ((NN + 255) >> 8)   // 391 buckets of 256 rows
#define CAP 8192                 // fixed bucket capacity (max observed ~4.5k)
#define BCHUNK 8192

typedef __attribute__((ext_vector_type(8))) short short8;
typedef __attribute__((ext_vector_type(4))) float f32x4;

__device__ inline unsigned short bf16_rne(float f) {
    unsigned u = __float_as_uint(f);
    return (unsigned short)((u + 0x7FFF + ((u >> 16) & 1)) >> 16);
}
__device__ inline float bf16_to_f32(unsigned short h) {
    return __uint_as_float((unsigned)h << 16);
}

// ---------------- fused setup: zero scratch + init bcur + weight transpose/convert ----------------
// fragment order: element (n,k) of W^T at ((k>>3)*8 + (n>>4))*128 + (n&15)*8 + (k&7)

__global__ void setup_kernel(const float* __restrict__ W0, const float* __restrict__ W1,
                             const float* __restrict__ W2, short* __restrict__ wt_hi,
                             int* __restrict__ bcur, float* __restrict__ colsum,
                             float* __restrict__ psum, float* __restrict__ pcnt) {
    int i = blockIdx.x * 256 + threadIdx.x;
    if (i < NBUK) bcur[i] = i * CAP;
    if (i < LL * HH * 2) colsum[i] = 0.f;
    if (i < GG * HH) psum[i] = 0.f;
    if (i < GG) pcnt[i] = 0.f;
    if (i < 9 * HH * HH) {
        int mat = i >> 14, rem = i & 16383;
        int n = rem >> 7, k = rem & 127;
        const float* src = (mat == 0) ? W0 : ((mat <= 4) ? W1 + (size_t)(mat - 1) * HH * HH
                                                         : W2 + (size_t)(mat - 5) * HH * HH);
        float v = src[(size_t)k * HH + n];
        int off = (mat << 14) + (((k >> 3) * 8 + (n >> 4)) << 7) + ((n & 15) << 3) + (k & 7);
        wt_hi[off] = (short)bf16_rne(v);
    }
}

// ---------------- CSR build: fixed-capacity bucket sort (256 rows / bucket) ----------------

__global__ __launch_bounds__(256) void bucket_scatter(const int* __restrict__ ei, int* __restrict__ bcur,
                                                      int* __restrict__ pairs) {
    __shared__ int h[NBUK];
    __shared__ int curb[NBUK];
    int tid = threadIdx.x;
    for (int i = tid; i < NBUK; i += 256) h[i] = 0;
    __syncthreads();
    int base = blockIdx.x * BCHUNK;
#pragma unroll 4
    for (int k = 0; k < BCHUNK / 256; k++) {
        int e = base + k * 256 + tid;
        if (e < 2 * EE) {
            int r = ei[e];
            int c = (e < EE) ? ei[e + EE] : ei[e - EE];
            if (r != c) atomicAdd(&h[r >> 8], 1);
        }
    }
    __syncthreads();
    for (int i = tid; i < NBUK; i += 256) {
        int n = h[i];
        curb[i] = n ? atomicAdd(&bcur[i], n) : 0;
    }
    __syncthreads();
#pragma unroll 4
    for (int k = 0; k < BCHUNK / 256; k++) {
        int e = base + k * 256 + tid;
        if (e < 2 * EE) {
            int r = ei[e];
            int c = (e < EE) ? ei[e + EE] : ei[e - EE];
            if (r != c) {
                int p = atomicAdd(&curb[r >> 8], 1);
                pairs[p] = ((r & 255) << 17) | c;
            }
        }
    }
}

__global__ __launch_bounds__(256) void bucket_build(const int* __restrict__ pairs, const int* __restrict__ bcur,
                                                    int* __restrict__ rp, int* __restrict__ re,
                                                    int* __restrict__ colidx) {
    __shared__ int hist[256], off[256], lcol[CAP];
    int b = blockIdx.x, tid = threadIdx.x;
    int s = b * CAP;
    int size = bcur[b] - s;
    hist[tid] = 0;
    __syncthreads();
    for (int i = tid; i < size; i += 256) atomicAdd(&hist[pairs[s + i] >> 17], 1);
    __syncthreads();
    off[tid] = hist[tid];
    __syncthreads();
    for (int o = 1; o < 256; o <<= 1) {
        int x = (tid >= o) ? off[tid - o] : 0;
        __syncthreads();
        off[tid] += x;
        __syncthreads();
    }
    int excl = (tid > 0) ? off[tid - 1] : 0;
    int r = (b << 8) + tid;
    if (r < NN) { rp[r] = s + excl; re[r] = s + off[tid]; }
    hist[tid] = excl;
    __syncthreads();
    for (int i = tid; i < size; i += 256) {
        int u = pairs[s + i];
        int p = atomicAdd(&hist[u >> 17], 1);
        lcol[p] = u & 0x1FFFF;
    }
    __syncthreads();
    for (int i = tid; i < size; i += 256) colidx[s + i] = lcol[i];
}

// ---------------- aggregation: u = (1+eps)*h + sum_nb h[nb], gather from bf16 h ----------------

__global__ __launch_bounds__(256) void agg_kernel(
    const unsigned int* __restrict__ hbf, const int* __restrict__ rp, const int* __restrict__ re,
    const int* __restrict__ colidx,
    const float* __restrict__ eps_l, int layer, float* __restrict__ u)
{
    int node = blockIdx.x * 4 + (threadIdx.x >> 6);
    if (node >= NN) return;
    int lane = threadIdx.x & 63;
    float eps1 = 1.0f + eps_l[layer];
    unsigned sv = hbf[node * 64 + lane];
    float ax = __uint_as_float(sv << 16) * eps1;
    float ay = __uint_as_float(sv & 0xFFFF0000u) * eps1;
    int i = rp[node], end = re[node];
    for (; i + 8 <= end; i += 8) {
        unsigned v[8];
#pragma unroll
        for (int j = 0; j < 8; j++) v[j] = hbf[colidx[i + j] * 64 + lane];
#pragma unroll
        for (int j = 0; j < 8; j++) {
            ax += __uint_as_float(v[j] << 16);
            ay += __uint_as_float(v[j] & 0xFFFF0000u);
        }
    }
    for (; i + 2 <= end; i += 2) {
        unsigned v0 = hbf[colidx[i] * 64 + lane];
        unsigned v1 = hbf[colidx[i + 1] * 64 + lane];
        ax += __uint_as_float(v0 << 16) + __uint_as_float(v1 << 16);
        ay += __uint_as_float(v0 & 0xFFFF0000u) + __uint_as_float(v1 & 0xFFFF0000u);
    }
    for (; i < end; i++) {
        unsigned v = hbf[colidx[i] * 64 + lane];
        ax += __uint_as_float(v << 16);
        ay += __uint_as_float(v & 0xFFFF0000u);
    }
    ((float2*)(u + (size_t)node * HH))[lane] = make_float2(ax, ay);
}

// ---------------- GEMM v8: 64 rows/block, W-hi(bf16) in LDS, A split-bf16, K-loop = LDS+MFMA only --
// MODE 0: hbf = bf16(x @ W0 + bias)                       [A fp32]
// MODE 1: z1  = bf16(A @ W1 + bias); column stats         [A = u, fp32]
// MODE 2: A' = relu(BN(z1)); hbf = bf16(LN(h_old + relu(A'@W2 + bias)))   [A = z1, bf16]

template<int MODE>
__global__ __launch_bounds__(256, 4) void gemm_v8(
    const void* __restrict__ Ain,
    const short* __restrict__ wt_hi,
    const float* __restrict__ bias,
    unsigned short* __restrict__ z1_out,
    float* __restrict__ colsum, float* __restrict__ colsq,
    const float* __restrict__ bng, const float* __restrict__ bnb,
    const float* __restrict__ lng, const float* __restrict__ lnb,
    unsigned short* __restrict__ hbf)
{
    __shared__ short wh[HH * HH];    // 32 KB W-hi; reused post-K-loop as bf16 row-tile stage
    __shared__ float stats[2 * HH];  // mode1: csum|csq ; mode2: bsc|bsh
    int tid = threadIdx.x;
    int wave = tid >> 6, lane = tid & 63;
    int lrow = lane & 15, kgrp = lane >> 4;
    int r0 = blockIdx.x * 64;
    int arow = r0 + wave * 16 + lrow;

    // stage W-hi (fragment order, coalesced, conflict-free)
    {
        const short8* src = (const short8*)wt_hi;
        short8* dst = (short8*)wh;
#pragma unroll
        for (int i = 0; i < 8; i++) dst[tid + i * 256] = src[tid + i * 256];
    }
    if (MODE == 1) stats[tid] = 0.f;
    if (MODE == 2 && tid < HH) {
        float m = colsum[tid] * (1.f / NN);
        float v = colsq[tid] * (1.f / NN) - m * m;
        float a = bng[tid] * rsqrtf(v + BN_EPS);
        stats[tid] = a;
        stats[HH + tid] = bnb[tid] - m * a;
    }

    // prefetch all A fragments
    float4 a0[4], a1[4];
    short8 az[4];
    if (MODE == 2) {
        const unsigned short* Az = (const unsigned short*)Ain;
        if (arow < NN) {
#pragma unroll
            for (int ks = 0; ks < 4; ks++)
                az[ks] = *(const short8*)(Az + (size_t)arow * HH + ks * 32 + kgrp * 8);
        } else {
#pragma unroll
            for (int ks = 0; ks < 4; ks++) az[ks] = (short8){0,0,0,0,0,0,0,0};
        }
    } else {
        const float* Af = (const float*)Ain;
        if (arow < NN) {
#pragma unroll
            for (int ks = 0; ks < 4; ks++) {
                int kb = ks * 32 + kgrp * 8;
                a0[ks] = *(const float4*)(Af + (size_t)arow * HH + kb);
                a1[ks] = *(const float4*)(Af + (size_t)arow * HH + kb + 4);
            }
        } else {
#pragma unroll
            for (int ks = 0; ks < 4; ks++) {
                a0[ks] = make_float4(0.f, 0.f, 0.f, 0.f);
                a1[ks] = a0[ks];
            }
        }
    }
    __syncthreads();

    f32x4 acc[8];
#pragma unroll
    for (int c = 0; c < 8; c++) acc[c] = (f32x4){0.f, 0.f, 0.f, 0.f};

#pragma unroll
    for (int ks = 0; ks < 4; ks++) {
        int kb = ks * 32 + kgrp * 8;
        float av[8];
        if (MODE == 2) {
#pragma unroll
            for (int j = 0; j < 8; j++) {
                float zb = bf16_to_f32((unsigned short)az[ks][j]);
                av[j] = fmaxf(fmaf(zb, stats[kb + j], stats[HH + kb + j]), 0.f);
            }
        } else {
            av[0] = a0[ks].x; av[1] = a0[ks].y; av[2] = a0[ks].z; av[3] = a0[ks].w;
            av[4] = a1[ks].x; av[5] = a1[ks].y; av[6] = a1[ks].z; av[7] = a1[ks].w;
        }
        short8 ahi, alo;
#pragma unroll
        for (int j = 0; j < 8; j++) {
            unsigned short hb = bf16_rne(av[j]);
            ahi[j] = (short)hb;
            alo[j] = (short)bf16_rne(av[j] - bf16_to_f32(hb));
        }
        int fb = (ks * 4 + kgrp) * 8;
#pragma unroll
        for (int c = 0; c < 8; c++) {
            short8 whi = *(const short8*)(wh + ((fb + c) << 7) + (lrow << 3));
            acc[c] = __builtin_amdgcn_mfma_f32_16x16x32_bf16(ahi, whi, acc[c], 0, 0, 0);
            acc[c] = __builtin_amdgcn_mfma_f32_16x16x32_bf16(alo, whi, acc[c], 0, 0, 0);
        }
    }

    float bv[8];
#pragma unroll
    for (int c = 0; c < 8; c++) bv[c] = bias[c * 16 + lrow];
    int lrb = wave * 16 + kgrp * 4;
    unsigned short* hst = (unsigned short*)wh;

    if (MODE == 0) {
        __syncthreads();
#pragma unroll
        for (int c = 0; c < 8; c++)
#pragma unroll
            for (int reg = 0; reg < 4; reg++)
                hst[(lrb + reg) * HH + c * 16 + lrow] = bf16_rne(acc[c][reg] + bv[c]);
        __syncthreads();
#pragma unroll
        for (int i = 0; i < 4; i++) {
            int idx = tid + i * 256;
            int r = r0 + (idx >> 4);
            if (r < NN)
                *(uint4*)(hbf + (size_t)r * HH + (idx & 15) * 8) = ((const uint4*)wh)[idx];
        }
    } else if (MODE == 1) {
        __syncthreads();
        float ps[8], pq[8];
#pragma unroll
        for (int c = 0; c < 8; c++) { ps[c] = 0.f; pq[c] = 0.f; }
#pragma unroll
        for (int c = 0; c < 8; c++)
#pragma unroll
            for (int reg = 0; reg < 4; reg++) {
                float z = acc[c][reg] + bv[c];
                hst[(lrb + reg) * HH + c * 16 + lrow] = bf16_rne(z);
                if (r0 + lrb + reg < NN) { ps[c] += z; pq[c] += z * z; }
            }
#pragma unroll
        for (int c = 0; c < 8; c++) {
            ps[c] += __shfl_xor(ps[c], 16); pq[c] += __shfl_xor(pq[c], 16);
            ps[c] += __shfl_xor(ps[c], 32); pq[c] += __shfl_xor(pq[c], 32);
        }
        if (kgrp == 0) {
#pragma unroll
            for (int c = 0; c < 8; c++) {
                atomicAdd(&stats[c * 16 + lrow], ps[c]);
                atomicAdd(&stats[HH + c * 16 + lrow], pq[c]);
            }
        }
        __syncthreads();
#pragma unroll
        for (int i = 0; i < 4; i++) {
            int idx = tid + i * 256;
            int r = r0 + (idx >> 4);
            if (r < NN)
                *(uint4*)(z1_out + (size_t)r * HH + (idx & 15) * 8) = ((const uint4*)wh)[idx];
        }
        if (tid < HH) {
            atomicAdd(&colsum[tid], stats[tid]);
            atomicAdd(&colsq[tid], stats[HH + tid]);
        }
    } else {
        float lg[8], lb[8];
#pragma unroll
        for (int c = 0; c < 8; c++) {
            lg[c] = lng[c * 16 + lrow];
            lb[c] = lnb[c * 16 + lrow];
        }
        __syncthreads();
        // coalesced load of old-h tile into LDS
#pragma unroll
        for (int i = 0; i < 4; i++) {
            int idx = tid + i * 256;
            int r = r0 + (idx >> 4);
            uint4 v = make_uint4(0, 0, 0, 0);
            if (r < NN) v = *(const uint4*)(hbf + (size_t)r * HH + (idx & 15) * 8);
            ((uint4*)wh)[idx] = v;
        }
        __syncthreads();
#pragma unroll
        for (int reg = 0; reg < 4; reg++) {
            int r = r0 + lrb + reg;
            if (r < NN) {   // uniform within each 16-lane shfl group
                float tv[8];
                float s = 0.f, q = 0.f;
#pragma unroll
                for (int c = 0; c < 8; c++) {
                    float hold = bf16_to_f32(hst[(lrb + reg) * HH + c * 16 + lrow]);
                    tv[c] = hold + fmaxf(acc[c][reg] + bv[c], 0.f);
                    s += tv[c]; q += tv[c] * tv[c];
                }
#pragma unroll
                for (int m = 1; m < 16; m <<= 1) {
                    s += __shfl_xor(s, m);
                    q += __shfl_xor(q, m);
                }
                float mu = s * (1.f / 128.f);
                float var = q * (1.f / 128.f) - mu * mu;
                float rs = rsqrtf(var + LN_EPS);
#pragma unroll
                for (int c = 0; c < 8; c++)
                    hst[(lrb + reg) * HH + c * 16 + lrow] =
                        bf16_rne((tv[c] - mu) * rs * lg[c] + lb[c]);
            }
        }
        __syncthreads();
#pragma unroll
        for (int i = 0; i < 4; i++) {
            int idx = tid + i * 256;
            int r = r0 + (idx >> 4);
            if (r < NN)
                *(uint4*)(hbf + (size_t)r * HH + (idx & 15) * 8) = ((const uint4*)wh)[idx];
        }
    }
}

// ---------------- pooling (reads bf16 h) ----------------

__global__ void pool_kernel(const unsigned short* __restrict__ h, const int* __restrict__ batch,
                            float* __restrict__ psum, float* __restrict__ pcnt)
{
    int t = threadIdx.x;  // 128
    int n0 = blockIdx.x * POOL_CHUNK;
    int n1 = n0 + POOL_CHUNK; if (n1 > NN) n1 = NN;
    if (n0 >= NN) return;
    float acc = 0.f;
    int cur = batch[n0];
    int cnt = 0;
    for (int n = n0; n < n1; n++) {
        int g = batch[n];
        if (g != cur) {
            atomicAdd(&psum[cur * HH + t], acc);
            if (t == 0) atomicAdd(&pcnt[cur], (float)cnt);
            acc = 0.f; cnt = 0; cur = g;
        }
        acc += bf16_to_f32(h[(size_t)n * HH + t]);
        cnt++;
    }
    atomicAdd(&psum[cur * HH + t], acc);
    if (t == 0) atomicAdd(&pcnt[cur], (float)cnt);
}

__global__ void pool_final(const float* __restrict__ psum, const float* __restrict__ pcnt,
                           float* __restrict__ out)
{
    int i = blockIdx.x * blockDim.x + threadIdx.x;
    if (i < GG * HH) {
        float c = pcnt[i >> 7];
        out[i] = psum[i] / fmaxf(c, 1.f);
    }
}

// ---------------- launch ----------------

extern "C" void kernel_launch(void* const* d_in, const int* in_sizes, int n_in,
                              void* d_out, int out_size, void* d_ws, size_t ws_size,
                              hipStream_t stream)
{
    const float* x     = (const float*)d_in[0];
    const float* W0    = (const float*)d_in[1];
    const float* b0    = (const float*)d_in[2];
    const float* eps_l = (const float*)d_in[3];
    const float* W1    = (const float*)d_in[4];
    const float* b1    = (const float*)d_in[5];
    const float* bng   = (const float*)d_in[6];
    const float* bnb   = (const float*)d_in[7];
    const float* W2    = (const float*)d_in[8];
    const float* b2    = (const float*)d_in[9];
    const float* lng   = (const float*)d_in[10];
    const float* lnb   = (const float*)d_in[11];
    const int*   ei    = (const int*)d_in[12];
    const int*   batch = (const int*)d_in[13];
    float* out = (float*)d_out;

    char* ws = (char*)d_ws;
    size_t off = 0;
    auto alloc = [&](size_t bytes) -> void* {
        void* p = ws + off;
        off += (bytes + 255) & ~(size_t)255;
        return p;
    };
    unsigned short* hbf = (unsigned short*)alloc((size_t)NN * HH * 2);  // h (bf16)
    unsigned short* z1  = (unsigned short*)alloc((size_t)NN * HH * 2);  // z1 (bf16)
    float* ubuf   = (float*)alloc((size_t)NN * HH * 4);                 // u (fp32)
    int*   colidx = (int*)alloc((size_t)NBUK * CAP * 4);
    int*   pairs  = (int*)alloc((size_t)NBUK * CAP * 4);
    int*   rp     = (int*)alloc((size_t)NN * 4);
    int*   re     = (int*)alloc((size_t)NN * 4);
    int*   bcur   = (int*)alloc((NBUK + 1) * 4);
    float* colsum = (float*)alloc((size_t)LL * HH * 2 * 4);  // [l][sum|sq][HH]
    float* psum   = (float*)alloc((size_t)GG * HH * 4);
    float* pcnt   = (float*)alloc(GG * 4);
    short* wt_hi  = (short*)alloc((size_t)9 * HH * HH * 2);

    // fused: zero colsum/psum/pcnt + bcur init + weight convert
    setup_kernel<<<(9 * HH * HH + 255) / 256, 256, 0, stream>>>(W0, W1, W2, wt_hi, bcur,
                                                                colsum, psum, pcnt);

    bucket_scatter<<<(2 * EE + BCHUNK - 1) / BCHUNK, 256, 0, stream>>>(ei, bcur, pairs);
    bucket_build<<<NBUK, 256, 0, stream>>>(pairs, bcur, rp, re, colidx);

    int gb = (NN + 63) / 64;
    // encode: h = bf16(x @ W0 + b0)
    gemm_v8<0><<<gb, 256, 0, stream>>>(x, wt_hi, b0, nullptr,
                                       nullptr, nullptr, nullptr, nullptr, nullptr, nullptr, hbf);

    for (int l = 0; l < LL; l++) {
        float* cs = colsum + (size_t)l * HH * 2;
        float* cq = cs + HH;
        // u = (1+eps)h + sum_nb h  (gather from bf16 h)
        agg_kernel<<<(NN + 3) / 4, 256, 0, stream>>>((const unsigned*)hbf, rp, re, colidx,
                                                     eps_l, l, ubuf);
        // z1 = bf16(u @ W1 + b1) + column stats
        gemm_v8<1><<<gb, 256, 0, stream>>>(ubuf, wt_hi + (size_t)(1 + l) * HH * HH,
                                           b1 + l * HH, z1,
                                           cs, cq, nullptr, nullptr, nullptr, nullptr, nullptr);
        // h = bf16(LN(h + relu(relu(BN(z1)) @ W2 + b2)))
        gemm_v8<2><<<gb, 256, 0, stream>>>(z1, wt_hi + (size_t)(5 + l) * HH * HH,
                                           b2 + l * HH, nullptr,
                                           cs, cq, bng + l * HH, bnb + l * HH,
                                           lng + l * HH, lnb + l * HH, hbf);
    }

    pool_kernel<<<(NN + POOL_CHUNK - 1) / POOL_CHUNK, 128, 0, stream>>>(hbf, batch, psum, pcnt);
    pool_final<<<(GG * HH + 255) / 256, 256, 0, stream>>>(psum, pcnt, out);
}

// Round 10
// 687.368 us; speedup vs baseline: 7.4945x; 1.0559x over previous
//
#include <hip/hip_runtime.h>

#define NN 100000
#define EE 800000
#define HH 128
#define LL 4
#define GG 64
#define BN_EPS 1e-5f
#define LN_EPS 1e-5f
#define POOL_CHUNK 64
#define NBUK ((NN + 255) >> 8)   // 391 buckets of 256 rows
#define CAP 8192                 // fixed bucket capacity (max observed ~4.5k)
#define BCHUNK 8192

typedef __attribute__((ext_vector_type(8))) short short8;
typedef __attribute__((ext_vector_type(4))) float f32x4;

__device__ inline unsigned short bf16_rne(float f) {
    unsigned u = __float_as_uint(f);
    return (unsigned short)((u + 0x7FFF + ((u >> 16) & 1)) >> 16);
}
__device__ inline float bf16_to_f32(unsigned short h) {
    return __uint_as_float((unsigned)h << 16);
}

// ---------------- fused setup: zero scratch + init bcur + weight transpose/convert ----------------
// fragment order: element (n,k) of W^T at ((k>>3)*8 + (n>>4))*128 + (n&15)*8 + (k&7)

__global__ void setup_kernel(const float* __restrict__ W0, const float* __restrict__ W1,
                             const float* __restrict__ W2, short* __restrict__ wt_hi,
                             int* __restrict__ bcur, float* __restrict__ colsum,
                             float* __restrict__ psum, float* __restrict__ pcnt) {
    int i = blockIdx.x * 256 + threadIdx.x;
    if (i < NBUK) bcur[i] = i * CAP;
    if (i < LL * HH * 2) colsum[i] = 0.f;
    if (i < GG * HH) psum[i] = 0.f;
    if (i < GG) pcnt[i] = 0.f;
    if (i < 9 * HH * HH) {
        int mat = i >> 14, rem = i & 16383;
        int n = rem >> 7, k = rem & 127;
        const float* src = (mat == 0) ? W0 : ((mat <= 4) ? W1 + (size_t)(mat - 1) * HH * HH
                                                         : W2 + (size_t)(mat - 5) * HH * HH);
        float v = src[(size_t)k * HH + n];
        int off = (mat << 14) + (((k >> 3) * 8 + (n >> 4)) << 7) + ((n & 15) << 3) + (k & 7);
        wt_hi[off] = (short)bf16_rne(v);
    }
}

// ---------------- CSR build: fixed-capacity bucket sort (256 rows / bucket) ----------------

__global__ __launch_bounds__(256) void bucket_scatter(const int* __restrict__ ei, int* __restrict__ bcur,
                                                      int* __restrict__ pairs) {
    __shared__ int h[NBUK];
    __shared__ int curb[NBUK];
    int tid = threadIdx.x;
    for (int i = tid; i < NBUK; i += 256) h[i] = 0;
    __syncthreads();
    int base = blockIdx.x * BCHUNK;
#pragma unroll 4
    for (int k = 0; k < BCHUNK / 256; k++) {
        int e = base + k * 256 + tid;
        if (e < 2 * EE) {
            int r = ei[e];
            int c = (e < EE) ? ei[e + EE] : ei[e - EE];
            if (r != c) atomicAdd(&h[r >> 8], 1);
        }
    }
    __syncthreads();
    for (int i = tid; i < NBUK; i += 256) {
        int n = h[i];
        curb[i] = n ? atomicAdd(&bcur[i], n) : 0;
    }
    __syncthreads();
#pragma unroll 4
    for (int k = 0; k < BCHUNK / 256; k++) {
        int e = base + k * 256 + tid;
        if (e < 2 * EE) {
            int r = ei[e];
            int c = (e < EE) ? ei[e + EE] : ei[e - EE];
            if (r != c) {
                int p = atomicAdd(&curb[r >> 8], 1);
                pairs[p] = ((r & 255) << 17) | c;
            }
        }
    }
}

__global__ __launch_bounds__(256) void bucket_build(const int* __restrict__ pairs, const int* __restrict__ bcur,
                                                    int* __restrict__ rp, int* __restrict__ re,
                                                    int* __restrict__ colidx) {
    __shared__ int hist[256], off[256], lcol[CAP];
    int b = blockIdx.x, tid = threadIdx.x;
    int s = b * CAP;
    int size = bcur[b] - s;
    hist[tid] = 0;
    __syncthreads();
    for (int i = tid; i < size; i += 256) atomicAdd(&hist[pairs[s + i] >> 17], 1);
    __syncthreads();
    off[tid] = hist[tid];
    __syncthreads();
    for (int o = 1; o < 256; o <<= 1) {
        int x = (tid >= o) ? off[tid - o] : 0;
        __syncthreads();
        off[tid] += x;
        __syncthreads();
    }
    int excl = (tid > 0) ? off[tid - 1] : 0;
    int r = (b << 8) + tid;
    if (r < NN) { rp[r] = s + excl; re[r] = s + off[tid]; }
    hist[tid] = excl;
    __syncthreads();
    for (int i = tid; i < size; i += 256) {
        int u = pairs[s + i];
        int p = atomicAdd(&hist[u >> 17], 1);
        lcol[p] = u & 0x1FFFF;
    }
    __syncthreads();
    for (int i = tid; i < size; i += 256) colidx[s + i] = lcol[i];
}

// ---------------- aggregation v2: 2 nodes/wave, uint2 gathers, bf16 u out ----------------
// u = bf16((1+eps)*h + sum_nb h[nb]); each half-wave (32 lanes x 8B) owns one node row.

__global__ __launch_bounds__(256) void agg_kernel(
    const uint2* __restrict__ hbf2, const int* __restrict__ rp, const int* __restrict__ re,
    const int* __restrict__ colidx,
    const float* __restrict__ eps_l, int layer, uint2* __restrict__ u2)
{
    int lane = threadIdx.x & 63;
    int half = lane >> 5, sub = lane & 31;
    int node = blockIdx.x * 8 + (threadIdx.x >> 6) * 2 + half;   // NN % 8 == 0
    float eps1 = 1.0f + eps_l[layer];
    uint2 sv = hbf2[(size_t)node * 32 + sub];
    float a0 = bf16_to_f32((unsigned short)(sv.x & 0xFFFF)) * eps1;
    float a1 = bf16_to_f32((unsigned short)(sv.x >> 16)) * eps1;
    float a2 = bf16_to_f32((unsigned short)(sv.y & 0xFFFF)) * eps1;
    float a3 = bf16_to_f32((unsigned short)(sv.y >> 16)) * eps1;
    int base = rp[node];
    int n = re[node] - base;
    for (int i = 0; i < n; i += 8) {
        uint2 v[8];
        int c[8];
#pragma unroll
        for (int j = 0; j < 8; j++) c[j] = (i + j < n) ? colidx[base + i + j] : -1;
#pragma unroll
        for (int j = 0; j < 8; j++)
            v[j] = (c[j] >= 0) ? hbf2[(size_t)c[j] * 32 + sub] : make_uint2(0u, 0u);
#pragma unroll
        for (int j = 0; j < 8; j++) {
            a0 += bf16_to_f32((unsigned short)(v[j].x & 0xFFFF));
            a1 += bf16_to_f32((unsigned short)(v[j].x >> 16));
            a2 += bf16_to_f32((unsigned short)(v[j].y & 0xFFFF));
            a3 += bf16_to_f32((unsigned short)(v[j].y >> 16));
        }
    }
    uint2 o;
    o.x = (unsigned)bf16_rne(a0) | ((unsigned)bf16_rne(a1) << 16);
    o.y = (unsigned)bf16_rne(a2) | ((unsigned)bf16_rne(a3) << 16);
    u2[(size_t)node * 32 + sub] = o;
}

// ---------------- GEMM v9: 64 rows/block, W(bf16) in LDS, K-loop = LDS+MFMA only ----------------
// MODE 0: hbf = bf16(x @ W0 + bias)                       [A fp32, split-bf16]
// MODE 1: z1  = bf16(A @ W1 + bias); column stats         [A = u bf16, direct]
// MODE 2: A' = relu(BN(z1)); hbf = bf16(LN(h_old + relu(A'@W2 + bias)))   [A = z1 bf16, split after BN]

template<int MODE>
__global__ __launch_bounds__(256, 4) void gemm_v9(
    const void* __restrict__ Ain,
    const short* __restrict__ wt_hi,
    const float* __restrict__ bias,
    unsigned short* __restrict__ z1_out,
    float* __restrict__ colsum, float* __restrict__ colsq,
    const float* __restrict__ bng, const float* __restrict__ bnb,
    const float* __restrict__ lng, const float* __restrict__ lnb,
    unsigned short* __restrict__ hbf)
{
    __shared__ short wh[HH * HH];    // 32 KB W; reused post-K-loop as bf16 row-tile stage
    __shared__ float stats[2 * HH];  // mode1: csum|csq ; mode2: bsc|bsh
    int tid = threadIdx.x;
    int wave = tid >> 6, lane = tid & 63;
    int lrow = lane & 15, kgrp = lane >> 4;
    int r0 = blockIdx.x * 64;
    int arow = r0 + wave * 16 + lrow;

    // stage W (fragment order, coalesced, conflict-free)
    {
        const short8* src = (const short8*)wt_hi;
        short8* dst = (short8*)wh;
#pragma unroll
        for (int i = 0; i < 8; i++) dst[tid + i * 256] = src[tid + i * 256];
    }
    if (MODE == 1) stats[tid] = 0.f;
    if (MODE == 2 && tid < HH) {
        float m = colsum[tid] * (1.f / NN);
        float v = colsq[tid] * (1.f / NN) - m * m;
        float a = bng[tid] * rsqrtf(v + BN_EPS);
        stats[tid] = a;
        stats[HH + tid] = bnb[tid] - m * a;
    }

    // prefetch all A fragments
    float4 a0[4], a1[4];
    short8 az[4];
    if (MODE != 0) {
        const unsigned short* Az = (const unsigned short*)Ain;
        if (arow < NN) {
#pragma unroll
            for (int ks = 0; ks < 4; ks++)
                az[ks] = *(const short8*)(Az + (size_t)arow * HH + ks * 32 + kgrp * 8);
        } else {
#pragma unroll
            for (int ks = 0; ks < 4; ks++) az[ks] = (short8){0,0,0,0,0,0,0,0};
        }
    } else {
        const float* Af = (const float*)Ain;
        if (arow < NN) {
#pragma unroll
            for (int ks = 0; ks < 4; ks++) {
                int kb = ks * 32 + kgrp * 8;
                a0[ks] = *(const float4*)(Af + (size_t)arow * HH + kb);
                a1[ks] = *(const float4*)(Af + (size_t)arow * HH + kb + 4);
            }
        } else {
#pragma unroll
            for (int ks = 0; ks < 4; ks++) {
                a0[ks] = make_float4(0.f, 0.f, 0.f, 0.f);
                a1[ks] = a0[ks];
            }
        }
    }
    __syncthreads();

    f32x4 acc[8];
#pragma unroll
    for (int c = 0; c < 8; c++) acc[c] = (f32x4){0.f, 0.f, 0.f, 0.f};

#pragma unroll
    for (int ks = 0; ks < 4; ks++) {
        int fb = (ks * 4 + kgrp) * 8;
        if (MODE == 1) {
            // A already bf16: feed directly, single MFMA per col-tile
#pragma unroll
            for (int c = 0; c < 8; c++) {
                short8 whi = *(const short8*)(wh + ((fb + c) << 7) + (lrow << 3));
                acc[c] = __builtin_amdgcn_mfma_f32_16x16x32_bf16(az[ks], whi, acc[c], 0, 0, 0);
            }
        } else {
            int kb = ks * 32 + kgrp * 8;
            float av[8];
            if (MODE == 2) {
#pragma unroll
                for (int j = 0; j < 8; j++) {
                    float zb = bf16_to_f32((unsigned short)az[ks][j]);
                    av[j] = fmaxf(fmaf(zb, stats[kb + j], stats[HH + kb + j]), 0.f);
                }
            } else {
                av[0] = a0[ks].x; av[1] = a0[ks].y; av[2] = a0[ks].z; av[3] = a0[ks].w;
                av[4] = a1[ks].x; av[5] = a1[ks].y; av[6] = a1[ks].z; av[7] = a1[ks].w;
            }
            short8 ahi, alo;
#pragma unroll
            for (int j = 0; j < 8; j++) {
                unsigned short hb = bf16_rne(av[j]);
                ahi[j] = (short)hb;
                alo[j] = (short)bf16_rne(av[j] - bf16_to_f32(hb));
            }
#pragma unroll
            for (int c = 0; c < 8; c++) {
                short8 whi = *(const short8*)(wh + ((fb + c) << 7) + (lrow << 3));
                acc[c] = __builtin_amdgcn_mfma_f32_16x16x32_bf16(ahi, whi, acc[c], 0, 0, 0);
                acc[c] = __builtin_amdgcn_mfma_f32_16x16x32_bf16(alo, whi, acc[c], 0, 0, 0);
            }
        }
    }

    float bv[8];
#pragma unroll
    for (int c = 0; c < 8; c++) bv[c] = bias[c * 16 + lrow];
    int lrb = wave * 16 + kgrp * 4;
    unsigned short* hst = (unsigned short*)wh;

    if (MODE == 0) {
        __syncthreads();
#pragma unroll
        for (int c = 0; c < 8; c++)
#pragma unroll
            for (int reg = 0; reg < 4; reg++)
                hst[(lrb + reg) * HH + c * 16 + lrow] = bf16_rne(acc[c][reg] + bv[c]);
        __syncthreads();
#pragma unroll
        for (int i = 0; i < 4; i++) {
            int idx = tid + i * 256;
            int r = r0 + (idx >> 4);
            if (r < NN)
                *(uint4*)(hbf + (size_t)r * HH + (idx & 15) * 8) = ((const uint4*)wh)[idx];
        }
    } else if (MODE == 1) {
        __syncthreads();
        float ps[8], pq[8];
#pragma unroll
        for (int c = 0; c < 8; c++) { ps[c] = 0.f; pq[c] = 0.f; }
#pragma unroll
        for (int c = 0; c < 8; c++)
#pragma unroll
            for (int reg = 0; reg < 4; reg++) {
                float z = acc[c][reg] + bv[c];
                hst[(lrb + reg) * HH + c * 16 + lrow] = bf16_rne(z);
                if (r0 + lrb + reg < NN) { ps[c] += z; pq[c] += z * z; }
            }
#pragma unroll
        for (int c = 0; c < 8; c++) {
            ps[c] += __shfl_xor(ps[c], 16); pq[c] += __shfl_xor(pq[c], 16);
            ps[c] += __shfl_xor(ps[c], 32); pq[c] += __shfl_xor(pq[c], 32);
        }
        if (kgrp == 0) {
#pragma unroll
            for (int c = 0; c < 8; c++) {
                atomicAdd(&stats[c * 16 + lrow], ps[c]);
                atomicAdd(&stats[HH + c * 16 + lrow], pq[c]);
            }
        }
        __syncthreads();
#pragma unroll
        for (int i = 0; i < 4; i++) {
            int idx = tid + i * 256;
            int r = r0 + (idx >> 4);
            if (r < NN)
                *(uint4*)(z1_out + (size_t)r * HH + (idx & 15) * 8) = ((const uint4*)wh)[idx];
        }
        if (tid < HH) {
            atomicAdd(&colsum[tid], stats[tid]);
            atomicAdd(&colsq[tid], stats[HH + tid]);
        }
    } else {
        float lg[8], lb[8];
#pragma unroll
        for (int c = 0; c < 8; c++) {
            lg[c] = lng[c * 16 + lrow];
            lb[c] = lnb[c * 16 + lrow];
        }
        __syncthreads();
        // coalesced load of old-h tile into LDS
#pragma unroll
        for (int i = 0; i < 4; i++) {
            int idx = tid + i * 256;
            int r = r0 + (idx >> 4);
            uint4 v = make_uint4(0, 0, 0, 0);
            if (r < NN) v = *(const uint4*)(hbf + (size_t)r * HH + (idx & 15) * 8);
            ((uint4*)wh)[idx] = v;
        }
        __syncthreads();
#pragma unroll
        for (int reg = 0; reg < 4; reg++) {
            int r = r0 + lrb + reg;
            if (r < NN) {   // uniform within each 16-lane shfl group
                float tv[8];
                float s = 0.f, q = 0.f;
#pragma unroll
                for (int c = 0; c < 8; c++) {
                    float hold = bf16_to_f32(hst[(lrb + reg) * HH + c * 16 + lrow]);
                    tv[c] = hold + fmaxf(acc[c][reg] + bv[c], 0.f);
                    s += tv[c]; q += tv[c] * tv[c];
                }
#pragma unroll
                for (int m = 1; m < 16; m <<= 1) {
                    s += __shfl_xor(s, m);
                    q += __shfl_xor(q, m);
                }
                float mu = s * (1.f / 128.f);
                float var = q * (1.f / 128.f) - mu * mu;
                float rs = rsqrtf(var + LN_EPS);
#pragma unroll
                for (int c = 0; c < 8; c++)
                    hst[(lrb + reg) * HH + c * 16 + lrow] =
                        bf16_rne((tv[c] - mu) * rs * lg[c] + lb[c]);
            }
        }
        __syncthreads();
#pragma unroll
        for (int i = 0; i < 4; i++) {
            int idx = tid + i * 256;
            int r = r0 + (idx >> 4);
            if (r < NN)
                *(uint4*)(hbf + (size_t)r * HH + (idx & 15) * 8) = ((const uint4*)wh)[idx];
        }
    }
}

// ---------------- pooling (reads bf16 h) ----------------

__global__ void pool_kernel(const unsigned short* __restrict__ h, const int* __restrict__ batch,
                            float* __restrict__ psum, float* __restrict__ pcnt)
{
    int t = threadIdx.x;  // 128
    int n0 = blockIdx.x * POOL_CHUNK;
    int n1 = n0 + POOL_CHUNK; if (n1 > NN) n1 = NN;
    if (n0 >= NN) return;
    float acc = 0.f;
    int cur = batch[n0];
    int cnt = 0;
    for (int n = n0; n < n1; n++) {
        int g = batch[n];
        if (g != cur) {
            atomicAdd(&psum[cur * HH + t], acc);
            if (t == 0) atomicAdd(&pcnt[cur], (float)cnt);
            acc = 0.f; cnt = 0; cur = g;
        }
        acc += bf16_to_f32(h[(size_t)n * HH + t]);
        cnt++;
    }
    atomicAdd(&psum[cur * HH + t], acc);
    if (t == 0) atomicAdd(&pcnt[cur], (float)cnt);
}

__global__ void pool_final(const float* __restrict__ psum, const float* __restrict__ pcnt,
                           float* __restrict__ out)
{
    int i = blockIdx.x * blockDim.x + threadIdx.x;
    if (i < GG * HH) {
        float c = pcnt[i >> 7];
        out[i] = psum[i] / fmaxf(c, 1.f);
    }
}

// ---------------- launch ----------------

extern "C" void kernel_launch(void* const* d_in, const int* in_sizes, int n_in,
                              void* d_out, int out_size, void* d_ws, size_t ws_size,
                              hipStream_t stream)
{
    const float* x     = (const float*)d_in[0];
    const float* W0    = (const float*)d_in[1];
    const float* b0    = (const float*)d_in[2];
    const float* eps_l = (const float*)d_in[3];
    const float* W1    = (const float*)d_in[4];
    const float* b1    = (const float*)d_in[5];
    const float* bng   = (const float*)d_in[6];
    const float* bnb   = (const float*)d_in[7];
    const float* W2    = (const float*)d_in[8];
    const float* b2    = (const float*)d_in[9];
    const float* lng   = (const float*)d_in[10];
    const float* lnb   = (const float*)d_in[11];
    const int*   ei    = (const int*)d_in[12];
    const int*   batch = (const int*)d_in[13];
    float* out = (float*)d_out;

    char* ws = (char*)d_ws;
    size_t off = 0;
    auto alloc = [&](size_t bytes) -> void* {
        void* p = ws + off;
        off += (bytes + 255) & ~(size_t)255;
        return p;
    };
    unsigned short* hbf = (unsigned short*)alloc((size_t)NN * HH * 2);  // h (bf16)
    unsigned short* z1  = (unsigned short*)alloc((size_t)NN * HH * 2);  // z1 (bf16)
    unsigned short* ubuf = (unsigned short*)alloc((size_t)NN * HH * 2); // u (bf16)
    int*   colidx = (int*)alloc((size_t)NBUK * CAP * 4 + 1024);         // +pad for 8-deep read
    int*   pairs  = (int*)alloc((size_t)NBUK * CAP * 4);
    int*   rp     = (int*)alloc((size_t)NN * 4);
    int*   re     = (int*)alloc((size_t)NN * 4);
    int*   bcur   = (int*)alloc((NBUK + 1) * 4);
    float* colsum = (float*)alloc((size_t)LL * HH * 2 * 4);  // [l][sum|sq][HH]
    float* psum   = (float*)alloc((size_t)GG * HH * 4);
    float* pcnt   = (float*)alloc(GG * 4);
    short* wt_hi  = (short*)alloc((size_t)9 * HH * HH * 2);

    // fused: zero colsum/psum/pcnt + bcur init + weight convert
    setup_kernel<<<(9 * HH * HH + 255) / 256, 256, 0, stream>>>(W0, W1, W2, wt_hi, bcur,
                                                                colsum, psum, pcnt);

    bucket_scatter<<<(2 * EE + BCHUNK - 1) / BCHUNK, 256, 0, stream>>>(ei, bcur, pairs);
    bucket_build<<<NBUK, 256, 0, stream>>>(pairs, bcur, rp, re, colidx);

    int gb = (NN + 63) / 64;
    // encode: h = bf16(x @ W0 + b0)
    gemm_v9<0><<<gb, 256, 0, stream>>>(x, wt_hi, b0, nullptr,
                                       nullptr, nullptr, nullptr, nullptr, nullptr, nullptr, hbf);

    for (int l = 0; l < LL; l++) {
        float* cs = colsum + (size_t)l * HH * 2;
        float* cq = cs + HH;
        // u = bf16((1+eps)h + sum_nb h)
        agg_kernel<<<NN / 8, 256, 0, stream>>>((const uint2*)hbf, rp, re, colidx,
                                               eps_l, l, (uint2*)ubuf);
        // z1 = bf16(u @ W1 + b1) + column stats
        gemm_v9<1><<<gb, 256, 0, stream>>>(ubuf, wt_hi + (size_t)(1 + l) * HH * HH,
                                           b1 + l * HH, z1,
                                           cs, cq, nullptr, nullptr, nullptr, nullptr, nullptr);
        // h = bf16(LN(h + relu(relu(BN(z1)) @ W2 + b2)))
        gemm_v9<2><<<gb, 256, 0, stream>>>(z1, wt_hi + (size_t)(5 + l) * HH * HH,
                                           b2 + l * HH, nullptr,
                                           cs, cq, bng + l * HH, bnb + l * HH,
                                           lng + l * HH, lnb + l * HH, hbf);
    }

    pool_kernel<<<(NN + POOL_CHUNK - 1) / POOL_CHUNK, 128, 0, stream>>>(hbf, batch, psum, pcnt);
    pool_final<<<(GG * HH + 255) / 256, 256, 0, stream>>>(psum, pcnt, out);
}

// Round 11
// 681.337 us; speedup vs baseline: 7.5609x; 1.0089x over previous
//
#include <hip/hip_runtime.h>

#define NN 100000
#define EE 800000
#define HH 128
#define LL 4
#define GG 64
#define BN_EPS 1e-5f
#define LN_EPS 1e-5f
#define POOL_CHUNK 64
#define NBUK ((NN + 255) >> 8)   // 391 buckets of 256 rows
#define CAP 8192                 // fixed bucket capacity (max observed ~4.5k)
#define BCHUNK 8192

typedef __attribute__((ext_vector_type(8))) short short8;
typedef __attribute__((ext_vector_type(4))) float f32x4;

__device__ inline unsigned short bf16_rne(float f) {
    unsigned u = __float_as_uint(f);
    return (unsigned short)((u + 0x7FFF + ((u >> 16) & 1)) >> 16);
}
__device__ inline float bf16_to_f32(unsigned short h) {
    return __uint_as_float((unsigned)h << 16);
}

// ---------------- fused setup: zero scratch + init bcur + weight transpose/convert ----------------
// fragment order: element (n,k) of W^T at ((k>>3)*8 + (n>>4))*128 + (n&15)*8 + (k&7)

__global__ void setup_kernel(const float* __restrict__ W0, const float* __restrict__ W1,
                             const float* __restrict__ W2, short* __restrict__ wt_hi,
                             int* __restrict__ bcur, float* __restrict__ colsum,
                             float* __restrict__ psum, float* __restrict__ pcnt) {
    int i = blockIdx.x * 256 + threadIdx.x;
    if (i < NBUK) bcur[i] = i * CAP;
    if (i < LL * HH * 2) colsum[i] = 0.f;
    if (i < GG * HH) psum[i] = 0.f;
    if (i < GG) pcnt[i] = 0.f;
    if (i < 9 * HH * HH) {
        int mat = i >> 14, rem = i & 16383;
        int n = rem >> 7, k = rem & 127;
        const float* src = (mat == 0) ? W0 : ((mat <= 4) ? W1 + (size_t)(mat - 1) * HH * HH
                                                         : W2 + (size_t)(mat - 5) * HH * HH);
        float v = src[(size_t)k * HH + n];
        int off = (mat << 14) + (((k >> 3) * 8 + (n >> 4)) << 7) + ((n & 15) << 3) + (k & 7);
        wt_hi[off] = (short)bf16_rne(v);
    }
}

// ---------------- CSR build: fixed-capacity bucket sort (256 rows / bucket) ----------------

__global__ __launch_bounds__(256) void bucket_scatter(const int* __restrict__ ei, int* __restrict__ bcur,
                                                      int* __restrict__ pairs) {
    __shared__ int h[NBUK];
    __shared__ int curb[NBUK];
    int tid = threadIdx.x;
    for (int i = tid; i < NBUK; i += 256) h[i] = 0;
    __syncthreads();
    int base = blockIdx.x * BCHUNK;
#pragma unroll 4
    for (int k = 0; k < BCHUNK / 256; k++) {
        int e = base + k * 256 + tid;
        if (e < 2 * EE) {
            int r = ei[e];
            int c = (e < EE) ? ei[e + EE] : ei[e - EE];
            if (r != c) atomicAdd(&h[r >> 8], 1);
        }
    }
    __syncthreads();
    for (int i = tid; i < NBUK; i += 256) {
        int n = h[i];
        curb[i] = n ? atomicAdd(&bcur[i], n) : 0;
    }
    __syncthreads();
#pragma unroll 4
    for (int k = 0; k < BCHUNK / 256; k++) {
        int e = base + k * 256 + tid;
        if (e < 2 * EE) {
            int r = ei[e];
            int c = (e < EE) ? ei[e + EE] : ei[e - EE];
            if (r != c) {
                int p = atomicAdd(&curb[r >> 8], 1);
                pairs[p] = ((r & 255) << 17) | c;
            }
        }
    }
}

__global__ __launch_bounds__(256) void bucket_build(const int* __restrict__ pairs, const int* __restrict__ bcur,
                                                    int* __restrict__ rp, int* __restrict__ re,
                                                    int* __restrict__ colidx) {
    __shared__ int hist[256], off[256], lcol[CAP];
    int b = blockIdx.x, tid = threadIdx.x;
    int s = b * CAP;
    int size = bcur[b] - s;
    hist[tid] = 0;
    __syncthreads();
    for (int i = tid; i < size; i += 256) atomicAdd(&hist[pairs[s + i] >> 17], 1);
    __syncthreads();
    off[tid] = hist[tid];
    __syncthreads();
    for (int o = 1; o < 256; o <<= 1) {
        int x = (tid >= o) ? off[tid - o] : 0;
        __syncthreads();
        off[tid] += x;
        __syncthreads();
    }
    int excl = (tid > 0) ? off[tid - 1] : 0;
    int r = (b << 8) + tid;
    if (r < NN) { rp[r] = s + excl; re[r] = s + off[tid]; }
    hist[tid] = excl;
    __syncthreads();
    for (int i = tid; i < size; i += 256) {
        int u = pairs[s + i];
        int p = atomicAdd(&hist[u >> 17], 1);
        lcol[p] = u & 0x1FFFF;
    }
    __syncthreads();
    for (int i = tid; i < size; i += 256) colidx[s + i] = lcol[i];
}

// ---------------- fused agg + GEMM1: 64 rows/block ----------------
// Phase A: each half-wave (32 lanes x 8B = one 256B row) gathers 8 rows serially,
//          8-deep pipelined, register accumulation (NO atomics), float4 -> LDS u-tile.
// Phase B: u-tile -> bf16 A-frags; LDS reused for W; MFMA; z1 = bf16(u@W1+b1) + col stats.

__global__ __launch_bounds__(256, 4) void fused_g1(
    const uint2* __restrict__ hbf2,
    const int* __restrict__ rp, const int* __restrict__ re,
    const int* __restrict__ colidx,
    const float* __restrict__ eps_l, int layer,
    const short* __restrict__ wt,
    const float* __restrict__ bias,
    unsigned short* __restrict__ z1_out,
    float* __restrict__ colsum, float* __restrict__ colsq)
{
    __shared__ __align__(16) char smem[64 * 132 * 4];   // u-tile (fp32), then W, then bf16 stage
    __shared__ float stats[2 * HH];
    float (*uls)[132] = (float(*)[132])smem;
    short* wh = (short*)smem;

    int tid = threadIdx.x;
    int wave = tid >> 6, lane = tid & 63;
    int half = lane >> 5, sub = lane & 31;
    int lrow = lane & 15, kgrp = lane >> 4;
    int r0 = blockIdx.x * 64;
    stats[tid] = 0.f;
    float eps1 = 1.0f + eps_l[layer];

    // ---- phase A: gather 8 rows per half-wave ----
    int hw = wave * 2 + half;   // 0..7
    for (int rl = 0; rl < 8; rl++) {
        int row = hw * 8 + rl;
        int r = r0 + row;
        float a0 = 0.f, a1 = 0.f, a2 = 0.f, a3 = 0.f;
        if (r < NN) {
            uint2 sv = hbf2[(size_t)r * 32 + sub];
            a0 = bf16_to_f32((unsigned short)(sv.x & 0xFFFF)) * eps1;
            a1 = bf16_to_f32((unsigned short)(sv.x >> 16)) * eps1;
            a2 = bf16_to_f32((unsigned short)(sv.y & 0xFFFF)) * eps1;
            a3 = bf16_to_f32((unsigned short)(sv.y >> 16)) * eps1;
            int base = rp[r];
            int n = re[r] - base;
            for (int i = 0; i < n; i += 8) {
                uint2 v[8];
                int c[8];
#pragma unroll
                for (int j = 0; j < 8; j++) c[j] = (i + j < n) ? colidx[base + i + j] : -1;
#pragma unroll
                for (int j = 0; j < 8; j++)
                    v[j] = (c[j] >= 0) ? hbf2[(size_t)c[j] * 32 + sub] : make_uint2(0u, 0u);
#pragma unroll
                for (int j = 0; j < 8; j++) {
                    a0 += bf16_to_f32((unsigned short)(v[j].x & 0xFFFF));
                    a1 += bf16_to_f32((unsigned short)(v[j].x >> 16));
                    a2 += bf16_to_f32((unsigned short)(v[j].y & 0xFFFF));
                    a3 += bf16_to_f32((unsigned short)(v[j].y >> 16));
                }
            }
        }
        *(float4*)&uls[row][sub * 4] = make_float4(a0, a1, a2, a3);
    }
    __syncthreads();

    // ---- A-frags from u-tile (bf16, matches u-as-bf16 numerics) ----
    short8 az[4];
#pragma unroll
    for (int ks = 0; ks < 4; ks++) {
        int kb = ks * 32 + kgrp * 8;
        float4 p0 = *(const float4*)&uls[wave * 16 + lrow][kb];
        float4 p1 = *(const float4*)&uls[wave * 16 + lrow][kb + 4];
        float av[8] = {p0.x, p0.y, p0.z, p0.w, p1.x, p1.y, p1.z, p1.w};
#pragma unroll
        for (int j = 0; j < 8; j++) az[ks][j] = (short)bf16_rne(av[j]);
    }
    __syncthreads();

    // ---- stage W (reuse LDS) ----
    {
        const short8* src = (const short8*)wt;
        short8* dst = (short8*)wh;
#pragma unroll
        for (int i = 0; i < 8; i++) dst[tid + i * 256] = src[tid + i * 256];
    }
    __syncthreads();

    f32x4 acc[8];
#pragma unroll
    for (int c = 0; c < 8; c++) acc[c] = (f32x4){0.f, 0.f, 0.f, 0.f};
#pragma unroll
    for (int ks = 0; ks < 4; ks++) {
        int fb = (ks * 4 + kgrp) * 8;
#pragma unroll
        for (int c = 0; c < 8; c++) {
            short8 whi = *(const short8*)(wh + ((fb + c) << 7) + (lrow << 3));
            acc[c] = __builtin_amdgcn_mfma_f32_16x16x32_bf16(az[ks], whi, acc[c], 0, 0, 0);
        }
    }

    // ---- epilogue: z1 bf16 out + column stats ----
    float bv[8];
#pragma unroll
    for (int c = 0; c < 8; c++) bv[c] = bias[c * 16 + lrow];
    int lrb = wave * 16 + kgrp * 4;
    unsigned short* hst = (unsigned short*)wh;
    __syncthreads();
    float ps[8], pq[8];
#pragma unroll
    for (int c = 0; c < 8; c++) { ps[c] = 0.f; pq[c] = 0.f; }
#pragma unroll
    for (int c = 0; c < 8; c++)
#pragma unroll
        for (int reg = 0; reg < 4; reg++) {
            float z = acc[c][reg] + bv[c];
            hst[(lrb + reg) * HH + c * 16 + lrow] = bf16_rne(z);
            if (r0 + lrb + reg < NN) { ps[c] += z; pq[c] += z * z; }
        }
#pragma unroll
    for (int c = 0; c < 8; c++) {
        ps[c] += __shfl_xor(ps[c], 16); pq[c] += __shfl_xor(pq[c], 16);
        ps[c] += __shfl_xor(ps[c], 32); pq[c] += __shfl_xor(pq[c], 32);
    }
    if (kgrp == 0) {
#pragma unroll
        for (int c = 0; c < 8; c++) {
            atomicAdd(&stats[c * 16 + lrow], ps[c]);
            atomicAdd(&stats[HH + c * 16 + lrow], pq[c]);
        }
    }
    __syncthreads();
#pragma unroll
    for (int i = 0; i < 4; i++) {
        int idx = tid + i * 256;
        int r = r0 + (idx >> 4);
        if (r < NN)
            *(uint4*)(z1_out + (size_t)r * HH + (idx & 15) * 8) = ((const uint4*)wh)[idx];
    }
    if (tid < HH) {
        atomicAdd(&colsum[tid], stats[tid]);
        atomicAdd(&colsq[tid], stats[HH + tid]);
    }
}

// ---------------- GEMM v9 (modes 0 and 2) ----------------
// MODE 0: hbf = bf16(x @ W0 + bias)                       [A fp32, split-bf16]
// MODE 2: A' = relu(BN(z1)); hbf = bf16(LN(h_old + relu(A'@W2 + bias)))   [A = z1 bf16]

template<int MODE>
__global__ __launch_bounds__(256, 4) void gemm_v9(
    const void* __restrict__ Ain,
    const short* __restrict__ wt_hi,
    const float* __restrict__ bias,
    float* __restrict__ colsum, float* __restrict__ colsq,
    const float* __restrict__ bng, const float* __restrict__ bnb,
    const float* __restrict__ lng, const float* __restrict__ lnb,
    unsigned short* __restrict__ hbf)
{
    __shared__ short wh[HH * HH];    // 32 KB W; reused post-K-loop as bf16 row-tile stage
    __shared__ float stats[2 * HH];  // mode2: bsc|bsh
    int tid = threadIdx.x;
    int wave = tid >> 6, lane = tid & 63;
    int lrow = lane & 15, kgrp = lane >> 4;
    int r0 = blockIdx.x * 64;
    int arow = r0 + wave * 16 + lrow;

    {
        const short8* src = (const short8*)wt_hi;
        short8* dst = (short8*)wh;
#pragma unroll
        for (int i = 0; i < 8; i++) dst[tid + i * 256] = src[tid + i * 256];
    }
    if (MODE == 2 && tid < HH) {
        float m = colsum[tid] * (1.f / NN);
        float v = colsq[tid] * (1.f / NN) - m * m;
        float a = bng[tid] * rsqrtf(v + BN_EPS);
        stats[tid] = a;
        stats[HH + tid] = bnb[tid] - m * a;
    }

    float4 a0[4], a1[4];
    short8 az[4];
    if (MODE == 2) {
        const unsigned short* Az = (const unsigned short*)Ain;
        if (arow < NN) {
#pragma unroll
            for (int ks = 0; ks < 4; ks++)
                az[ks] = *(const short8*)(Az + (size_t)arow * HH + ks * 32 + kgrp * 8);
        } else {
#pragma unroll
            for (int ks = 0; ks < 4; ks++) az[ks] = (short8){0,0,0,0,0,0,0,0};
        }
    } else {
        const float* Af = (const float*)Ain;
        if (arow < NN) {
#pragma unroll
            for (int ks = 0; ks < 4; ks++) {
                int kb = ks * 32 + kgrp * 8;
                a0[ks] = *(const float4*)(Af + (size_t)arow * HH + kb);
                a1[ks] = *(const float4*)(Af + (size_t)arow * HH + kb + 4);
            }
        } else {
#pragma unroll
            for (int ks = 0; ks < 4; ks++) {
                a0[ks] = make_float4(0.f, 0.f, 0.f, 0.f);
                a1[ks] = a0[ks];
            }
        }
    }
    __syncthreads();

    f32x4 acc[8];
#pragma unroll
    for (int c = 0; c < 8; c++) acc[c] = (f32x4){0.f, 0.f, 0.f, 0.f};

#pragma unroll
    for (int ks = 0; ks < 4; ks++) {
        int fb = (ks * 4 + kgrp) * 8;
        int kb = ks * 32 + kgrp * 8;
        float av[8];
        if (MODE == 2) {
#pragma unroll
            for (int j = 0; j < 8; j++) {
                float zb = bf16_to_f32((unsigned short)az[ks][j]);
                av[j] = fmaxf(fmaf(zb, stats[kb + j], stats[HH + kb + j]), 0.f);
            }
        } else {
            av[0] = a0[ks].x; av[1] = a0[ks].y; av[2] = a0[ks].z; av[3] = a0[ks].w;
            av[4] = a1[ks].x; av[5] = a1[ks].y; av[6] = a1[ks].z; av[7] = a1[ks].w;
        }
        short8 ahi, alo;
#pragma unroll
        for (int j = 0; j < 8; j++) {
            unsigned short hb = bf16_rne(av[j]);
            ahi[j] = (short)hb;
            alo[j] = (short)bf16_rne(av[j] - bf16_to_f32(hb));
        }
#pragma unroll
        for (int c = 0; c < 8; c++) {
            short8 whi = *(const short8*)(wh + ((fb + c) << 7) + (lrow << 3));
            acc[c] = __builtin_amdgcn_mfma_f32_16x16x32_bf16(ahi, whi, acc[c], 0, 0, 0);
            acc[c] = __builtin_amdgcn_mfma_f32_16x16x32_bf16(alo, whi, acc[c], 0, 0, 0);
        }
    }

    float bv[8];
#pragma unroll
    for (int c = 0; c < 8; c++) bv[c] = bias[c * 16 + lrow];
    int lrb = wave * 16 + kgrp * 4;
    unsigned short* hst = (unsigned short*)wh;

    if (MODE == 0) {
        __syncthreads();
#pragma unroll
        for (int c = 0; c < 8; c++)
#pragma unroll
            for (int reg = 0; reg < 4; reg++)
                hst[(lrb + reg) * HH + c * 16 + lrow] = bf16_rne(acc[c][reg] + bv[c]);
        __syncthreads();
#pragma unroll
        for (int i = 0; i < 4; i++) {
            int idx = tid + i * 256;
            int r = r0 + (idx >> 4);
            if (r < NN)
                *(uint4*)(hbf + (size_t)r * HH + (idx & 15) * 8) = ((const uint4*)wh)[idx];
        }
    } else {
        float lg[8], lb[8];
#pragma unroll
        for (int c = 0; c < 8; c++) {
            lg[c] = lng[c * 16 + lrow];
            lb[c] = lnb[c * 16 + lrow];
        }
        __syncthreads();
        // coalesced load of old-h tile into LDS
#pragma unroll
        for (int i = 0; i < 4; i++) {
            int idx = tid + i * 256;
            int r = r0 + (idx >> 4);
            uint4 v = make_uint4(0, 0, 0, 0);
            if (r < NN) v = *(const uint4*)(hbf + (size_t)r * HH + (idx & 15) * 8);
            ((uint4*)wh)[idx] = v;
        }
        __syncthreads();
#pragma unroll
        for (int reg = 0; reg < 4; reg++) {
            int r = r0 + lrb + reg;
            if (r < NN) {   // uniform within each 16-lane shfl group
                float tv[8];
                float s = 0.f, q = 0.f;
#pragma unroll
                for (int c = 0; c < 8; c++) {
                    float hold = bf16_to_f32(hst[(lrb + reg) * HH + c * 16 + lrow]);
                    tv[c] = hold + fmaxf(acc[c][reg] + bv[c], 0.f);
                    s += tv[c]; q += tv[c] * tv[c];
                }
#pragma unroll
                for (int m = 1; m < 16; m <<= 1) {
                    s += __shfl_xor(s, m);
                    q += __shfl_xor(q, m);
                }
                float mu = s * (1.f / 128.f);
                float var = q * (1.f / 128.f) - mu * mu;
                float rs = rsqrtf(var + LN_EPS);
#pragma unroll
                for (int c = 0; c < 8; c++)
                    hst[(lrb + reg) * HH + c * 16 + lrow] =
                        bf16_rne((tv[c] - mu) * rs * lg[c] + lb[c]);
            }
        }
        __syncthreads();
#pragma unroll
        for (int i = 0; i < 4; i++) {
            int idx = tid + i * 256;
            int r = r0 + (idx >> 4);
            if (r < NN)
                *(uint4*)(hbf + (size_t)r * HH + (idx & 15) * 8) = ((const uint4*)wh)[idx];
        }
    }
}

// ---------------- pooling (reads bf16 h) ----------------

__global__ void pool_kernel(const unsigned short* __restrict__ h, const int* __restrict__ batch,
                            float* __restrict__ psum, float* __restrict__ pcnt)
{
    int t = threadIdx.x;  // 128
    int n0 = blockIdx.x * POOL_CHUNK;
    int n1 = n0 + POOL_CHUNK; if (n1 > NN) n1 = NN;
    if (n0 >= NN) return;
    float acc = 0.f;
    int cur = batch[n0];
    int cnt = 0;
    for (int n = n0; n < n1; n++) {
        int g = batch[n];
        if (g != cur) {
            atomicAdd(&psum[cur * HH + t], acc);
            if (t == 0) atomicAdd(&pcnt[cur], (float)cnt);
            acc = 0.f; cnt = 0; cur = g;
        }
        acc += bf16_to_f32(h[(size_t)n * HH + t]);
        cnt++;
    }
    atomicAdd(&psum[cur * HH + t], acc);
    if (t == 0) atomicAdd(&pcnt[cur], (float)cnt);
}

__global__ void pool_final(const float* __restrict__ psum, const float* __restrict__ pcnt,
                           float* __restrict__ out)
{
    int i = blockIdx.x * blockDim.x + threadIdx.x;
    if (i < GG * HH) {
        float c = pcnt[i >> 7];
        out[i] = psum[i] / fmaxf(c, 1.f);
    }
}

// ---------------- launch ----------------

extern "C" void kernel_launch(void* const* d_in, const int* in_sizes, int n_in,
                              void* d_out, int out_size, void* d_ws, size_t ws_size,
                              hipStream_t stream)
{
    const float* x     = (const float*)d_in[0];
    const float* W0    = (const float*)d_in[1];
    const float* b0    = (const float*)d_in[2];
    const float* eps_l = (const float*)d_in[3];
    const float* W1    = (const float*)d_in[4];
    const float* b1    = (const float*)d_in[5];
    const float* bng   = (const float*)d_in[6];
    const float* bnb   = (const float*)d_in[7];
    const float* W2    = (const float*)d_in[8];
    const float* b2    = (const float*)d_in[9];
    const float* lng   = (const float*)d_in[10];
    const float* lnb   = (const float*)d_in[11];
    const int*   ei    = (const int*)d_in[12];
    const int*   batch = (const int*)d_in[13];
    float* out = (float*)d_out;

    char* ws = (char*)d_ws;
    size_t off = 0;
    auto alloc = [&](size_t bytes) -> void* {
        void* p = ws + off;
        off += (bytes + 255) & ~(size_t)255;
        return p;
    };
    unsigned short* hbf = (unsigned short*)alloc((size_t)NN * HH * 2);  // h (bf16)
    unsigned short* z1  = (unsigned short*)alloc((size_t)NN * HH * 2);  // z1 (bf16)
    int*   colidx = (int*)alloc((size_t)NBUK * CAP * 4 + 1024);         // +pad for 8-deep read
    int*   pairs  = (int*)alloc((size_t)NBUK * CAP * 4);
    int*   rp     = (int*)alloc((size_t)NN * 4);
    int*   re     = (int*)alloc((size_t)NN * 4);
    int*   bcur   = (int*)alloc((NBUK + 1) * 4);
    float* colsum = (float*)alloc((size_t)LL * HH * 2 * 4);  // [l][sum|sq][HH]
    float* psum   = (float*)alloc((size_t)GG * HH * 4);
    float* pcnt   = (float*)alloc(GG * 4);
    short* wt_hi  = (short*)alloc((size_t)9 * HH * HH * 2);

    // fused: zero colsum/psum/pcnt + bcur init + weight convert
    setup_kernel<<<(9 * HH * HH + 255) / 256, 256, 0, stream>>>(W0, W1, W2, wt_hi, bcur,
                                                                colsum, psum, pcnt);

    bucket_scatter<<<(2 * EE + BCHUNK - 1) / BCHUNK, 256, 0, stream>>>(ei, bcur, pairs);
    bucket_build<<<NBUK, 256, 0, stream>>>(pairs, bcur, rp, re, colidx);

    int gb = (NN + 63) / 64;
    // encode: h = bf16(x @ W0 + b0)
    gemm_v9<0><<<gb, 256, 0, stream>>>(x, wt_hi, b0,
                                       nullptr, nullptr, nullptr, nullptr, nullptr, nullptr, hbf);

    for (int l = 0; l < LL; l++) {
        float* cs = colsum + (size_t)l * HH * 2;
        float* cq = cs + HH;
        // z1 = bf16(((1+eps)h + sum_nb h) @ W1 + b1) + col stats  (agg fused, u never hits HBM)
        fused_g1<<<gb, 256, 0, stream>>>((const uint2*)hbf, rp, re, colidx, eps_l, l,
                                         wt_hi + (size_t)(1 + l) * HH * HH, b1 + l * HH, z1,
                                         cs, cq);
        // h = bf16(LN(h + relu(relu(BN(z1)) @ W2 + b2)))
        gemm_v9<2><<<gb, 256, 0, stream>>>(z1, wt_hi + (size_t)(5 + l) * HH * HH,
                                           b2 + l * HH,
                                           cs, cq, bng + l * HH, bnb + l * HH,
                                           lng + l * HH, lnb + l * HH, hbf);
    }

    pool_kernel<<<(NN + POOL_CHUNK - 1) / POOL_CHUNK, 128, 0, stream>>>(hbf, batch, psum, pcnt);
    pool_final<<<(GG * HH + 255) / 256, 256, 0, stream>>>(psum, pcnt, out);
}

// Round 12
// 674.530 us; speedup vs baseline: 7.6372x; 1.0101x over previous
//
#include <hip/hip_runtime.h>

#define NN 100000
#define EE 800000
#define HH 128
#define LL 4
#define GG 64
#define BN_EPS 1e-5f
#define LN_EPS 1e-5f
#define POOL_CHUNK 64
#define NBUK ((NN + 255) >> 8)   // 391 buckets of 256 rows
#define CAP 8192                 // fixed bucket capacity (max observed ~4.5k)
#define BCHUNK 8192
#define UPITCH 136               // u-tile row pitch in shorts (128 + 8 pad)

typedef __attribute__((ext_vector_type(8))) short short8;
typedef __attribute__((ext_vector_type(4))) float f32x4;

__device__ inline unsigned short bf16_rne(float f) {
    unsigned u = __float_as_uint(f);
    return (unsigned short)((u + 0x7FFF + ((u >> 16) & 1)) >> 16);
}
__device__ inline float bf16_to_f32(unsigned short h) {
    return __uint_as_float((unsigned)h << 16);
}

// ---------------- fused setup: zero scratch + init bcur + weight transpose/convert ----------------
// fragment order: element (n,k) of W^T at ((k>>3)*8 + (n>>4))*128 + (n&15)*8 + (k&7)

__global__ void setup_kernel(const float* __restrict__ W0, const float* __restrict__ W1,
                             const float* __restrict__ W2, short* __restrict__ wt_hi,
                             int* __restrict__ bcur, float* __restrict__ colsum,
                             float* __restrict__ psum, float* __restrict__ pcnt) {
    int i = blockIdx.x * 256 + threadIdx.x;
    if (i < NBUK) bcur[i] = i * CAP;
    if (i < LL * HH * 2) colsum[i] = 0.f;
    if (i < GG * HH) psum[i] = 0.f;
    if (i < GG) pcnt[i] = 0.f;
    if (i < 9 * HH * HH) {
        int mat = i >> 14, rem = i & 16383;
        int n = rem >> 7, k = rem & 127;
        const float* src = (mat == 0) ? W0 : ((mat <= 4) ? W1 + (size_t)(mat - 1) * HH * HH
                                                         : W2 + (size_t)(mat - 5) * HH * HH);
        float v = src[(size_t)k * HH + n];
        int off = (mat << 14) + (((k >> 3) * 8 + (n >> 4)) << 7) + ((n & 15) << 3) + (k & 7);
        wt_hi[off] = (short)bf16_rne(v);
    }
}

// ---------------- CSR build: fixed-capacity bucket sort (256 rows / bucket) ----------------

__global__ __launch_bounds__(256) void bucket_scatter(const int* __restrict__ ei, int* __restrict__ bcur,
                                                      int* __restrict__ pairs) {
    __shared__ int h[NBUK];
    __shared__ int curb[NBUK];
    int tid = threadIdx.x;
    for (int i = tid; i < NBUK; i += 256) h[i] = 0;
    __syncthreads();
    int base = blockIdx.x * BCHUNK;
#pragma unroll 4
    for (int k = 0; k < BCHUNK / 256; k++) {
        int e = base + k * 256 + tid;
        if (e < 2 * EE) {
            int r = ei[e];
            int c = (e < EE) ? ei[e + EE] : ei[e - EE];
            if (r != c) atomicAdd(&h[r >> 8], 1);
        }
    }
    __syncthreads();
    for (int i = tid; i < NBUK; i += 256) {
        int n = h[i];
        curb[i] = n ? atomicAdd(&bcur[i], n) : 0;
    }
    __syncthreads();
#pragma unroll 4
    for (int k = 0; k < BCHUNK / 256; k++) {
        int e = base + k * 256 + tid;
        if (e < 2 * EE) {
            int r = ei[e];
            int c = (e < EE) ? ei[e + EE] : ei[e - EE];
            if (r != c) {
                int p = atomicAdd(&curb[r >> 8], 1);
                pairs[p] = ((r & 255) << 17) | c;
            }
        }
    }
}

__global__ __launch_bounds__(256) void bucket_build(const int* __restrict__ pairs, const int* __restrict__ bcur,
                                                    int* __restrict__ rp, int* __restrict__ re,
                                                    int* __restrict__ colidx) {
    __shared__ int hist[256], off[256], lcol[CAP];
    int b = blockIdx.x, tid = threadIdx.x;
    int s = b * CAP;
    int size = bcur[b] - s;
    hist[tid] = 0;
    __syncthreads();
    for (int i = tid; i < size; i += 256) atomicAdd(&hist[pairs[s + i] >> 17], 1);
    __syncthreads();
    off[tid] = hist[tid];
    __syncthreads();
    for (int o = 1; o < 256; o <<= 1) {
        int x = (tid >= o) ? off[tid - o] : 0;
        __syncthreads();
        off[tid] += x;
        __syncthreads();
    }
    int excl = (tid > 0) ? off[tid - 1] : 0;
    int r = (b << 8) + tid;
    if (r < NN) { rp[r] = s + excl; re[r] = s + off[tid]; }
    hist[tid] = excl;
    __syncthreads();
    for (int i = tid; i < size; i += 256) {
        int u = pairs[s + i];
        int p = atomicAdd(&hist[u >> 17], 1);
        lcol[p] = u & 0x1FFFF;
    }
    __syncthreads();
    for (int i = tid; i < size; i += 256) colidx[s + i] = lcol[i];
}

// ---------------- fused agg + GEMM1 v2: 64 rows/block, small LDS, high occupancy ----------------
// Phase A: half-wave (32 lanes x 8B = one 256B row) gathers 8 rows serially, 8-deep pipelined,
//          register accumulation, bf16 -> LDS u-tile (17 KB).
// Phase B: u-tile -> bf16 A-frags; W read from global (L1-resident, fragment order); MFMA;
//          z1 = bf16(u@W1+b1) staged through same LDS; column stats.

__global__ __launch_bounds__(256, 6) void fused_g1(
    const uint2* __restrict__ hbf2,
    const int* __restrict__ rp, const int* __restrict__ re,
    const int* __restrict__ colidx,
    const float* __restrict__ eps_l, int layer,
    const short* __restrict__ wt,
    const float* __restrict__ bias,
    unsigned short* __restrict__ z1_out,
    float* __restrict__ colsum, float* __restrict__ colsq)
{
    __shared__ __align__(16) unsigned short uls[64 * UPITCH];   // 17.4 KB bf16 u-tile / z1 stage
    __shared__ float stats[2 * HH];
    int tid = threadIdx.x;
    int wave = tid >> 6, lane = tid & 63;
    int half = lane >> 5, sub = lane & 31;
    int lrow = lane & 15, kgrp = lane >> 4;
    int r0 = blockIdx.x * 64;
    stats[tid] = 0.f;
    float eps1 = 1.0f + eps_l[layer];

    // ---- phase A: gather 8 rows per half-wave ----
    int hw = wave * 2 + half;   // 0..7
    for (int rl = 0; rl < 8; rl++) {
        int row = hw * 8 + rl;
        int r = r0 + row;
        float a0 = 0.f, a1 = 0.f, a2 = 0.f, a3 = 0.f;
        if (r < NN) {
            uint2 sv = hbf2[(size_t)r * 32 + sub];
            a0 = bf16_to_f32((unsigned short)(sv.x & 0xFFFF)) * eps1;
            a1 = bf16_to_f32((unsigned short)(sv.x >> 16)) * eps1;
            a2 = bf16_to_f32((unsigned short)(sv.y & 0xFFFF)) * eps1;
            a3 = bf16_to_f32((unsigned short)(sv.y >> 16)) * eps1;
            int base = rp[r];
            int n = re[r] - base;
            for (int i = 0; i < n; i += 8) {
                uint2 v[8];
                int c[8];
#pragma unroll
                for (int j = 0; j < 8; j++) c[j] = (i + j < n) ? colidx[base + i + j] : -1;
#pragma unroll
                for (int j = 0; j < 8; j++)
                    v[j] = (c[j] >= 0) ? hbf2[(size_t)c[j] * 32 + sub] : make_uint2(0u, 0u);
#pragma unroll
                for (int j = 0; j < 8; j++) {
                    a0 += bf16_to_f32((unsigned short)(v[j].x & 0xFFFF));
                    a1 += bf16_to_f32((unsigned short)(v[j].x >> 16));
                    a2 += bf16_to_f32((unsigned short)(v[j].y & 0xFFFF));
                    a3 += bf16_to_f32((unsigned short)(v[j].y >> 16));
                }
            }
        }
        uint2 o;
        o.x = (unsigned)bf16_rne(a0) | ((unsigned)bf16_rne(a1) << 16);
        o.y = (unsigned)bf16_rne(a2) | ((unsigned)bf16_rne(a3) << 16);
        *(uint2*)&uls[row * UPITCH + sub * 4] = o;
    }
    __syncthreads();

    // ---- A-frags from bf16 u-tile ----
    short8 az[4];
#pragma unroll
    for (int ks = 0; ks < 4; ks++)
        az[ks] = *(const short8*)&uls[(wave * 16 + lrow) * UPITCH + ks * 32 + kgrp * 8];
    __syncthreads();   // frag reads done; uls reusable for z1 staging

    // ---- MFMA: W from global (32 KB, L1-resident, fragment order) ----
    f32x4 acc[8];
#pragma unroll
    for (int c = 0; c < 8; c++) acc[c] = (f32x4){0.f, 0.f, 0.f, 0.f};
#pragma unroll
    for (int ks = 0; ks < 4; ks++) {
        int fb = (ks * 4 + kgrp) * 8;
#pragma unroll
        for (int c = 0; c < 8; c++) {
            short8 whi = *(const short8*)(wt + (size_t)((fb + c) << 7) + (lrow << 3));
            acc[c] = __builtin_amdgcn_mfma_f32_16x16x32_bf16(az[ks], whi, acc[c], 0, 0, 0);
        }
    }

    // ---- epilogue: z1 bf16 out (staged through uls) + column stats ----
    float bv[8];
#pragma unroll
    for (int c = 0; c < 8; c++) bv[c] = bias[c * 16 + lrow];
    int lrb = wave * 16 + kgrp * 4;
    float ps[8], pq[8];
#pragma unroll
    for (int c = 0; c < 8; c++) { ps[c] = 0.f; pq[c] = 0.f; }
#pragma unroll
    for (int c = 0; c < 8; c++)
#pragma unroll
        for (int reg = 0; reg < 4; reg++) {
            float z = acc[c][reg] + bv[c];
            uls[(lrb + reg) * UPITCH + c * 16 + lrow] = bf16_rne(z);
            if (r0 + lrb + reg < NN) { ps[c] += z; pq[c] += z * z; }
        }
#pragma unroll
    for (int c = 0; c < 8; c++) {
        ps[c] += __shfl_xor(ps[c], 16); pq[c] += __shfl_xor(pq[c], 16);
        ps[c] += __shfl_xor(ps[c], 32); pq[c] += __shfl_xor(pq[c], 32);
    }
    if (kgrp == 0) {
#pragma unroll
        for (int c = 0; c < 8; c++) {
            atomicAdd(&stats[c * 16 + lrow], ps[c]);
            atomicAdd(&stats[HH + c * 16 + lrow], pq[c]);
        }
    }
    __syncthreads();
#pragma unroll
    for (int i = 0; i < 4; i++) {
        int idx = tid + i * 256;
        int row = idx >> 4;
        int r = r0 + row;
        if (r < NN)
            *(uint4*)(z1_out + (size_t)r * HH + (idx & 15) * 8) =
                *(const uint4*)&uls[row * UPITCH + (idx & 15) * 8];
    }
    if (tid < HH) {
        atomicAdd(&colsum[tid], stats[tid]);
        atomicAdd(&colsq[tid], stats[HH + tid]);
    }
}

// ---------------- GEMM v9 (modes 0 and 2) ----------------
// MODE 0: hbf = bf16(x @ W0 + bias)                       [A fp32, split-bf16]
// MODE 2: A' = relu(BN(z1)); hbf = bf16(LN(h_old + relu(A'@W2 + bias)))   [A = z1 bf16]

template<int MODE>
__global__ __launch_bounds__(256, 4) void gemm_v9(
    const void* __restrict__ Ain,
    const short* __restrict__ wt_hi,
    const float* __restrict__ bias,
    float* __restrict__ colsum, float* __restrict__ colsq,
    const float* __restrict__ bng, const float* __restrict__ bnb,
    const float* __restrict__ lng, const float* __restrict__ lnb,
    unsigned short* __restrict__ hbf)
{
    __shared__ short wh[HH * HH];    // 32 KB W; reused post-K-loop as bf16 row-tile stage
    __shared__ float stats[2 * HH];  // mode2: bsc|bsh
    int tid = threadIdx.x;
    int wave = tid >> 6, lane = tid & 63;
    int lrow = lane & 15, kgrp = lane >> 4;
    int r0 = blockIdx.x * 64;
    int arow = r0 + wave * 16 + lrow;

    {
        const short8* src = (const short8*)wt_hi;
        short8* dst = (short8*)wh;
#pragma unroll
        for (int i = 0; i < 8; i++) dst[tid + i * 256] = src[tid + i * 256];
    }
    if (MODE == 2 && tid < HH) {
        float m = colsum[tid] * (1.f / NN);
        float v = colsq[tid] * (1.f / NN) - m * m;
        float a = bng[tid] * rsqrtf(v + BN_EPS);
        stats[tid] = a;
        stats[HH + tid] = bnb[tid] - m * a;
    }

    float4 a0[4], a1[4];
    short8 az[4];
    if (MODE == 2) {
        const unsigned short* Az = (const unsigned short*)Ain;
        if (arow < NN) {
#pragma unroll
            for (int ks = 0; ks < 4; ks++)
                az[ks] = *(const short8*)(Az + (size_t)arow * HH + ks * 32 + kgrp * 8);
        } else {
#pragma unroll
            for (int ks = 0; ks < 4; ks++) az[ks] = (short8){0,0,0,0,0,0,0,0};
        }
    } else {
        const float* Af = (const float*)Ain;
        if (arow < NN) {
#pragma unroll
            for (int ks = 0; ks < 4; ks++) {
                int kb = ks * 32 + kgrp * 8;
                a0[ks] = *(const float4*)(Af + (size_t)arow * HH + kb);
                a1[ks] = *(const float4*)(Af + (size_t)arow * HH + kb + 4);
            }
        } else {
#pragma unroll
            for (int ks = 0; ks < 4; ks++) {
                a0[ks] = make_float4(0.f, 0.f, 0.f, 0.f);
                a1[ks] = a0[ks];
            }
        }
    }
    __syncthreads();

    f32x4 acc[8];
#pragma unroll
    for (int c = 0; c < 8; c++) acc[c] = (f32x4){0.f, 0.f, 0.f, 0.f};

#pragma unroll
    for (int ks = 0; ks < 4; ks++) {
        int fb = (ks * 4 + kgrp) * 8;
        int kb = ks * 32 + kgrp * 8;
        float av[8];
        if (MODE == 2) {
#pragma unroll
            for (int j = 0; j < 8; j++) {
                float zb = bf16_to_f32((unsigned short)az[ks][j]);
                av[j] = fmaxf(fmaf(zb, stats[kb + j], stats[HH + kb + j]), 0.f);
            }
        } else {
            av[0] = a0[ks].x; av[1] = a0[ks].y; av[2] = a0[ks].z; av[3] = a0[ks].w;
            av[4] = a1[ks].x; av[5] = a1[ks].y; av[6] = a1[ks].z; av[7] = a1[ks].w;
        }
        short8 ahi, alo;
#pragma unroll
        for (int j = 0; j < 8; j++) {
            unsigned short hb = bf16_rne(av[j]);
            ahi[j] = (short)hb;
            alo[j] = (short)bf16_rne(av[j] - bf16_to_f32(hb));
        }
#pragma unroll
        for (int c = 0; c < 8; c++) {
            short8 whi = *(const short8*)(wh + ((fb + c) << 7) + (lrow << 3));
            acc[c] = __builtin_amdgcn_mfma_f32_16x16x32_bf16(ahi, whi, acc[c], 0, 0, 0);
            acc[c] = __builtin_amdgcn_mfma_f32_16x16x32_bf16(alo, whi, acc[c], 0, 0, 0);
        }
    }

    float bv[8];
#pragma unroll
    for (int c = 0; c < 8; c++) bv[c] = bias[c * 16 + lrow];
    int lrb = wave * 16 + kgrp * 4;
    unsigned short* hst = (unsigned short*)wh;

    if (MODE == 0) {
        __syncthreads();
#pragma unroll
        for (int c = 0; c < 8; c++)
#pragma unroll
            for (int reg = 0; reg < 4; reg++)
                hst[(lrb + reg) * HH + c * 16 + lrow] = bf16_rne(acc[c][reg] + bv[c]);
        __syncthreads();
#pragma unroll
        for (int i = 0; i < 4; i++) {
            int idx = tid + i * 256;
            int r = r0 + (idx >> 4);
            if (r < NN)
                *(uint4*)(hbf + (size_t)r * HH + (idx & 15) * 8) = ((const uint4*)wh)[idx];
        }
    } else {
        float lg[8], lb[8];
#pragma unroll
        for (int c = 0; c < 8; c++) {
            lg[c] = lng[c * 16 + lrow];
            lb[c] = lnb[c * 16 + lrow];
        }
        __syncthreads();
        // coalesced load of old-h tile into LDS
#pragma unroll
        for (int i = 0; i < 4; i++) {
            int idx = tid + i * 256;
            int r = r0 + (idx >> 4);
            uint4 v = make_uint4(0, 0, 0, 0);
            if (r < NN) v = *(const uint4*)(hbf + (size_t)r * HH + (idx & 15) * 8);
            ((uint4*)wh)[idx] = v;
        }
        __syncthreads();
#pragma unroll
        for (int reg = 0; reg < 4; reg++) {
            int r = r0 + lrb + reg;
            if (r < NN) {   // uniform within each 16-lane shfl group
                float tv[8];
                float s = 0.f, q = 0.f;
#pragma unroll
                for (int c = 0; c < 8; c++) {
                    float hold = bf16_to_f32(hst[(lrb + reg) * HH + c * 16 + lrow]);
                    tv[c] = hold + fmaxf(acc[c][reg] + bv[c], 0.f);
                    s += tv[c]; q += tv[c] * tv[c];
                }
#pragma unroll
                for (int m = 1; m < 16; m <<= 1) {
                    s += __shfl_xor(s, m);
                    q += __shfl_xor(q, m);
                }
                float mu = s * (1.f / 128.f);
                float var = q * (1.f / 128.f) - mu * mu;
                float rs = rsqrtf(var + LN_EPS);
#pragma unroll
                for (int c = 0; c < 8; c++)
                    hst[(lrb + reg) * HH + c * 16 + lrow] =
                        bf16_rne((tv[c] - mu) * rs * lg[c] + lb[c]);
            }
        }
        __syncthreads();
#pragma unroll
        for (int i = 0; i < 4; i++) {
            int idx = tid + i * 256;
            int r = r0 + (idx >> 4);
            if (r < NN)
                *(uint4*)(hbf + (size_t)r * HH + (idx & 15) * 8) = ((const uint4*)wh)[idx];
        }
    }
}

// ---------------- pooling (reads bf16 h) ----------------

__global__ void pool_kernel(const unsigned short* __restrict__ h, const int* __restrict__ batch,
                            float* __restrict__ psum, float* __restrict__ pcnt)
{
    int t = threadIdx.x;  // 128
    int n0 = blockIdx.x * POOL_CHUNK;
    int n1 = n0 + POOL_CHUNK; if (n1 > NN) n1 = NN;
    if (n0 >= NN) return;
    float acc = 0.f;
    int cur = batch[n0];
    int cnt = 0;
    for (int n = n0; n < n1; n++) {
        int g = batch[n];
        if (g != cur) {
            atomicAdd(&psum[cur * HH + t], acc);
            if (t == 0) atomicAdd(&pcnt[cur], (float)cnt);
            acc = 0.f; cnt = 0; cur = g;
        }
        acc += bf16_to_f32(h[(size_t)n * HH + t]);
        cnt++;
    }
    atomicAdd(&psum[cur * HH + t], acc);
    if (t == 0) atomicAdd(&pcnt[cur], (float)cnt);
}

__global__ void pool_final(const float* __restrict__ psum, const float* __restrict__ pcnt,
                           float* __restrict__ out)
{
    int i = blockIdx.x * blockDim.x + threadIdx.x;
    if (i < GG * HH) {
        float c = pcnt[i >> 7];
        out[i] = psum[i] / fmaxf(c, 1.f);
    }
}

// ---------------- launch ----------------

extern "C" void kernel_launch(void* const* d_in, const int* in_sizes, int n_in,
                              void* d_out, int out_size, void* d_ws, size_t ws_size,
                              hipStream_t stream)
{
    const float* x     = (const float*)d_in[0];
    const float* W0    = (const float*)d_in[1];
    const float* b0    = (const float*)d_in[2];
    const float* eps_l = (const float*)d_in[3];
    const float* W1    = (const float*)d_in[4];
    const float* b1    = (const float*)d_in[5];
    const float* bng   = (const float*)d_in[6];
    const float* bnb   = (const float*)d_in[7];
    const float* W2    = (const float*)d_in[8];
    const float* b2    = (const float*)d_in[9];
    const float* lng   = (const float*)d_in[10];
    const float* lnb   = (const float*)d_in[11];
    const int*   ei    = (const int*)d_in[12];
    const int*   batch = (const int*)d_in[13];
    float* out = (float*)d_out;

    char* ws = (char*)d_ws;
    size_t off = 0;
    auto alloc = [&](size_t bytes) -> void* {
        void* p = ws + off;
        off += (bytes + 255) & ~(size_t)255;
        return p;
    };
    unsigned short* hbf = (unsigned short*)alloc((size_t)NN * HH * 2);  // h (bf16)
    unsigned short* z1  = (unsigned short*)alloc((size_t)NN * HH * 2);  // z1 (bf16)
    int*   colidx = (int*)alloc((size_t)NBUK * CAP * 4 + 1024);         // +pad for 8-deep read
    int*   pairs  = (int*)alloc((size_t)NBUK * CAP * 4);
    int*   rp     = (int*)alloc((size_t)NN * 4);
    int*   re     = (int*)alloc((size_t)NN * 4);
    int*   bcur   = (int*)alloc((NBUK + 1) * 4);
    float* colsum = (float*)alloc((size_t)LL * HH * 2 * 4);  // [l][sum|sq][HH]
    float* psum   = (float*)alloc((size_t)GG * HH * 4);
    float* pcnt   = (float*)alloc(GG * 4);
    short* wt_hi  = (short*)alloc((size_t)9 * HH * HH * 2);

    // fused: zero colsum/psum/pcnt + bcur init + weight convert
    setup_kernel<<<(9 * HH * HH + 255) / 256, 256, 0, stream>>>(W0, W1, W2, wt_hi, bcur,
                                                                colsum, psum, pcnt);

    bucket_scatter<<<(2 * EE + BCHUNK - 1) / BCHUNK, 256, 0, stream>>>(ei, bcur, pairs);
    bucket_build<<<NBUK, 256, 0, stream>>>(pairs, bcur, rp, re, colidx);

    int gb = (NN + 63) / 64;
    // encode: h = bf16(x @ W0 + b0)
    gemm_v9<0><<<gb, 256, 0, stream>>>(x, wt_hi, b0,
                                       nullptr, nullptr, nullptr, nullptr, nullptr, nullptr, hbf);

    for (int l = 0; l < LL; l++) {
        float* cs = colsum + (size_t)l * HH * 2;
        float* cq = cs + HH;
        // z1 = bf16(((1+eps)h + sum_nb h) @ W1 + b1) + col stats  (agg fused, u never hits HBM)
        fused_g1<<<gb, 256, 0, stream>>>((const uint2*)hbf, rp, re, colidx, eps_l, l,
                                         wt_hi + (size_t)(1 + l) * HH * HH, b1 + l * HH, z1,
                                         cs, cq);
        // h = bf16(LN(h + relu(relu(BN(z1)) @ W2 + b2)))
        gemm_v9<2><<<gb, 256, 0, stream>>>(z1, wt_hi + (size_t)(5 + l) * HH * HH,
                                           b2 + l * HH,
                                           cs, cq, bng + l * HH, bnb + l * HH,
                                           lng + l * HH, lnb + l * HH, hbf);
    }

    pool_kernel<<<(NN + POOL_CHUNK - 1) / POOL_CHUNK, 128, 0, stream>>>(hbf, batch, psum, pcnt);
    pool_final<<<(GG * HH + 255) / 256, 256, 0, stream>>>(psum, pcnt, out);
}